// Round 5
// baseline (778.363 us; speedup 1.0000x reference)
//
#include <hip/hip_runtime.h>
#include <hip/hip_bf16.h>

#define N_NODES 50000
#define N_EDGES 800000
#define IN_FEAT 100
#define OUT_FEAT 100
#define NUM_RELS 200
#define NUM_HEADS 3

#define KP 128          // padded K (100 -> 128)
#define NPH 112         // per-head padded N (100 -> 112 = 7*16)
#define NP  336         // 3 * 112
#define MB  128         // edges (or node-rows) per block
#define NT_O 7          // NPH/16

// ---- workspace layout (bytes) ----
#define WS_B       0u           // fc_w^T bf16 image [n=336][kstorage=128]: 86016
#define WS_LW      86016u       // loop_w^T bf16 image [112][128]: 28672
#define WS_CNT     114688u      // 50176 ints
#define WS_OFFS    315392u
#define WS_CURSOR  516096u
#define WS_BSUM    716800u      // 64 ints
#define WS_PERM    717056u      // 800000 ints
#define WS_FEAT    3917056u     // bf16 feat rows, 112 ushorts (224 B) each
#define NNODES_PAD 50176        // 49*1024

typedef __attribute__((ext_vector_type(8))) short short8;
typedef __attribute__((ext_vector_type(4))) float f32x4;

__device__ __forceinline__ unsigned short f2bf(float f) {
    unsigned u = __builtin_bit_cast(unsigned, f);
    unsigned r = u + 0x7FFFu + ((u >> 16) & 1u);
    return (unsigned short)(r >> 16);
}
__device__ __forceinline__ float bf2f(unsigned hs) {
    return __builtin_bit_cast(float, hs << 16);
}

// ---------------------------------------------------------------------------
// Weight images, LINEAR layout (read directly from L1/L2 by MFMA fragments).
// granule g (=kt*4+g4) at ushort offset n*KP + g*8; elem j in [0,8):
//   k = kt*32 + (j>>2)*16 + g4*4 + (j&3)   -- matches A-fragment packing.
// ---------------------------------------------------------------------------
__global__ __launch_bounds__(256) void build_B(const float* __restrict__ fc_w,
                                               unsigned short* __restrict__ Bws) {
    int idx = blockIdx.x * 256 + threadIdx.x;     // granule id: n*16 + g
    if (idx >= NP * 16) return;
    int n = idx >> 4, g = idx & 15;
    int head = n / NPH, nl = n - head * NPH;
    int kt = g >> 2, g4 = g & 3;
    unsigned p[4];
#pragma unroll
    for (int half = 0; half < 2; ++half) {
#pragma unroll
        for (int jp = 0; jp < 2; ++jp) {
            int k_lo = kt * 32 + half * 16 + g4 * 4 + jp * 2;
            int k_hi = k_lo + 1;
            float vlo = (k_lo < IN_FEAT && nl < OUT_FEAT)
                      ? fc_w[k_lo * (OUT_FEAT * NUM_HEADS) + head * OUT_FEAT + nl] : 0.f;
            float vhi = (k_hi < IN_FEAT && nl < OUT_FEAT)
                      ? fc_w[k_hi * (OUT_FEAT * NUM_HEADS) + head * OUT_FEAT + nl] : 0.f;
            p[half * 2 + jp] = (unsigned)f2bf(vlo) | ((unsigned)f2bf(vhi) << 16);
        }
    }
    reinterpret_cast<int4*>(Bws)[idx] = make_int4((int)p[0], (int)p[1], (int)p[2], (int)p[3]);
}

__global__ __launch_bounds__(256) void build_LW(const float* __restrict__ loop_w,
                                                unsigned short* __restrict__ LWws) {
    int idx = blockIdx.x * 256 + threadIdx.x;
    if (idx >= NPH * 16) return;
    int nl = idx >> 4, g = idx & 15;
    int kt = g >> 2, g4 = g & 3;
    unsigned p[4];
#pragma unroll
    for (int half = 0; half < 2; ++half) {
#pragma unroll
        for (int jp = 0; jp < 2; ++jp) {
            int k_lo = kt * 32 + half * 16 + g4 * 4 + jp * 2;
            int k_hi = k_lo + 1;
            float vlo = (k_lo < IN_FEAT && nl < OUT_FEAT) ? loop_w[k_lo * OUT_FEAT + nl] : 0.f;
            float vhi = (k_hi < IN_FEAT && nl < OUT_FEAT) ? loop_w[k_hi * OUT_FEAT + nl] : 0.f;
            p[half * 2 + jp] = (unsigned)f2bf(vlo) | ((unsigned)f2bf(vhi) << 16);
        }
    }
    reinterpret_cast<int4*>(LWws)[idx] = make_int4((int)p[0], (int)p[1], (int)p[2], (int)p[3]);
}

// ---------------------------------------------------------------------------
// Self-loop GEMM: out = h @ loop_w. Zero LDS, zero barriers; LW from L2.
// ---------------------------------------------------------------------------
__global__ __launch_bounds__(512, 2) void loop_gemm(const float* __restrict__ h,
                                                    const unsigned short* __restrict__ LWimg,
                                                    float* __restrict__ out) {
    const int tid = threadIdx.x;
    const int wave = tid >> 6, lane = tid & 63;
    const int lrow = lane & 15, lk = lane >> 4;
    const int rbase = blockIdx.x * MB;
    const int grow = rbase + wave * 16 + lrow;
    const bool ok = grow < N_NODES;
    const float* ap = h + (size_t)grow * IN_FEAT;

    short8 afrag[4];
#pragma unroll
    for (int kt = 0; kt < 4; ++kt) {
        int k0 = kt * 32 + lk * 4, k1 = k0 + 16;
        float4 va = (ok && k0 + 4 <= IN_FEAT) ? *reinterpret_cast<const float4*>(ap + k0)
                                              : make_float4(0.f, 0.f, 0.f, 0.f);
        float4 vb = (ok && k1 + 4 <= IN_FEAT) ? *reinterpret_cast<const float4*>(ap + k1)
                                              : make_float4(0.f, 0.f, 0.f, 0.f);
        afrag[kt][0] = (short)f2bf(va.x); afrag[kt][1] = (short)f2bf(va.y);
        afrag[kt][2] = (short)f2bf(va.z); afrag[kt][3] = (short)f2bf(va.w);
        afrag[kt][4] = (short)f2bf(vb.x); afrag[kt][5] = (short)f2bf(vb.y);
        afrag[kt][6] = (short)f2bf(vb.z); afrag[kt][7] = (short)f2bf(vb.w);
    }

#pragma unroll
    for (int nt = 0; nt < NT_O; ++nt) {
        f32x4 acc = (f32x4){0.f, 0.f, 0.f, 0.f};
#pragma unroll
        for (int kt = 0; kt < 4; ++kt) {
            short8 bfrag = *reinterpret_cast<const short8*>(
                LWimg + ((nt * 16 + lrow) * KP + kt * 32 + lk * 8));
            acc = __builtin_amdgcn_mfma_f32_16x16x32_bf16(afrag[kt], bfrag, acc, 0, 0, 0);
        }
        int o = nt * 16 + lrow;
        if (o < OUT_FEAT) {
#pragma unroll
            for (int r = 0; r < 4; ++r) {
                int crow = rbase + wave * 16 + lk * 4 + r;
                if (crow < N_NODES) out[(size_t)crow * OUT_FEAT + o] = acc[r];
            }
        }
    }
}

// ---------------------------------------------------------------------------
// CSR construction
// ---------------------------------------------------------------------------
__global__ __launch_bounds__(512) void hist_kernel(const int* __restrict__ dst,
                                                   int* __restrict__ cnt) {
    int e = blockIdx.x * 512 + threadIdx.x;
    if (e < N_EDGES) atomicAdd(&cnt[dst[e]], 1);
}

__global__ __launch_bounds__(1024) void scan1(const int* __restrict__ cnt,
                                              int* __restrict__ offs,
                                              int* __restrict__ bsum) {
    __shared__ int s[1024];
    int i = blockIdx.x * 1024 + threadIdx.x;
    int v = (i < N_NODES) ? cnt[i] : 0;
    s[threadIdx.x] = v;
    __syncthreads();
    for (int d = 1; d < 1024; d <<= 1) {
        int t = (threadIdx.x >= d) ? s[threadIdx.x - d] : 0;
        __syncthreads();
        s[threadIdx.x] += t;
        __syncthreads();
    }
    offs[i] = s[threadIdx.x] - v;
    if (threadIdx.x == 1023) bsum[blockIdx.x] = s[1023];
}

__global__ __launch_bounds__(64) void scan2(int* __restrict__ bsum) {
    __shared__ int s[64];
    int v = (threadIdx.x < NNODES_PAD / 1024) ? bsum[threadIdx.x] : 0;
    s[threadIdx.x] = v;
    __syncthreads();
    for (int d = 1; d < 64; d <<= 1) {
        int t = (threadIdx.x >= d) ? s[threadIdx.x - d] : 0;
        __syncthreads();
        s[threadIdx.x] += t;
        __syncthreads();
    }
    bsum[threadIdx.x] = s[threadIdx.x] - v;
}

__global__ __launch_bounds__(1024) void scan3(int* __restrict__ offs,
                                              const int* __restrict__ bsum,
                                              int* __restrict__ cursor) {
    int i = blockIdx.x * 1024 + threadIdx.x;
    int v = offs[i] + bsum[blockIdx.x];
    offs[i] = v;
    cursor[i] = v;
}

__global__ __launch_bounds__(512) void scatter_kernel(const int* __restrict__ dst,
                                                      int* __restrict__ cursor,
                                                      int* __restrict__ perm) {
    int e = blockIdx.x * 512 + threadIdx.x;
    if (e < N_EDGES) {
        int p = atomicAdd(&cursor[dst[e]], 1);
        perm[p] = e;
    }
}

// ---------------------------------------------------------------------------
// feat kernel v5: ZERO barriers. A in registers (coalesced efeat rows),
// B fragments direct from L2/L1-resident global image, acc folded per head.
// Only LDS: per-wave private 3.5 KB transpose slice (intra-wave, lgkmcnt only).
// ---------------------------------------------------------------------------
template<bool TOWS>
__global__ __launch_bounds__(512, 2) void feat_kernel(
        const float* __restrict__ efeat, const int* __restrict__ rel,
        const unsigned short* __restrict__ Bimg, const float* __restrict__ attn,
        const float* __restrict__ h, const float* __restrict__ weight,
        const float* __restrict__ norm, const int* __restrict__ src,
        const int* __restrict__ dst, float* __restrict__ out,
        unsigned short* __restrict__ featws, int lo) {

    __shared__ unsigned short slice[8][16 * NPH];   // 8 x 3584 B, per-wave private

    const int tid = threadIdx.x;
    const int wave = tid >> 6, lane = tid & 63;
    const int lrow = lane & 15, lk = lane >> 4;
    const int ebase = lo + blockIdx.x * MB;
    const int arow = ebase + wave * 16 + lrow;
    const float* ap = efeat + (size_t)arow * IN_FEAT;

    // ---- A fragments: registers, coalesced row reads ----
    short8 afrag[4];
#pragma unroll
    for (int kt = 0; kt < 4; ++kt) {
        int k0 = kt * 32 + lk * 4, k1 = k0 + 16;
        float4 va = (k0 + 4 <= IN_FEAT) ? *reinterpret_cast<const float4*>(ap + k0)
                                        : make_float4(0.f, 0.f, 0.f, 0.f);
        float4 vb = (k1 + 4 <= IN_FEAT) ? *reinterpret_cast<const float4*>(ap + k1)
                                        : make_float4(0.f, 0.f, 0.f, 0.f);
        afrag[kt][0] = (short)f2bf(va.x); afrag[kt][1] = (short)f2bf(va.y);
        afrag[kt][2] = (short)f2bf(va.z); afrag[kt][3] = (short)f2bf(va.w);
        afrag[kt][4] = (short)f2bf(vb.x); afrag[kt][5] = (short)f2bf(vb.y);
        afrag[kt][6] = (short)f2bf(vb.z); afrag[kt][7] = (short)f2bf(vb.w);
    }

    // relations of this lane's 4 C-rows (quarter-wave broadcast loads)
    const float* at_r[4];
#pragma unroll
    for (int r = 0; r < 4; ++r)
        at_r[r] = attn + (size_t)rel[ebase + wave * 16 + lk * 4 + r] * (NUM_HEADS * OUT_FEAT);

    float feat[NT_O][4];
#pragma unroll
    for (int nt = 0; nt < NT_O; ++nt)
#pragma unroll
        for (int r = 0; r < 4; ++r) feat[nt][r] = 0.f;

    // ---- main loop: B direct from global (L1-hot 4 KB panels), fold per head ----
#pragma unroll 1
    for (int hh = 0; hh < NUM_HEADS; ++hh) {
        const unsigned short* Bh = Bimg + (size_t)hh * (NPH * KP);
#pragma unroll
        for (int nt = 0; nt < NT_O; ++nt) {
            f32x4 acc = (f32x4){0.f, 0.f, 0.f, 0.f};
#pragma unroll
            for (int kt = 0; kt < 4; ++kt) {
                short8 bfrag = *reinterpret_cast<const short8*>(
                    Bh + ((nt * 16 + lrow) * KP + kt * 32 + lk * 8));
                acc = __builtin_amdgcn_mfma_f32_16x16x32_bf16(afrag[kt], bfrag, acc, 0, 0, 0);
            }
            int o = nt * 16 + lrow;
            if (o < OUT_FEAT) {
                int oo = hh * OUT_FEAT + o;
#pragma unroll
                for (int r = 0; r < 4; ++r) {
                    float v = acc[r] * at_r[r][oo];
                    feat[nt][r] += (v > 0.f) ? v : 0.2f * v;
                }
            }
        }
    }

    if (TOWS) {
        // per-wave transpose through private LDS slice (no cross-wave sync)
        unsigned short* sl = slice[wave];
#pragma unroll
        for (int nt = 0; nt < NT_O; ++nt) {
            int o = nt * 16 + lrow;
#pragma unroll
            for (int r = 0; r < 4; ++r)
                sl[(lk * 4 + r) * NPH + o] = f2bf(feat[nt][r]);
        }
        asm volatile("s_waitcnt lgkmcnt(0)" ::: "memory");
        __builtin_amdgcn_sched_barrier(0);
        // coalesced writeout: 16 rows x 224 B = 224 int4, contiguous in featws
        const int4* sp = reinterpret_cast<const int4*>(sl);
        int4* gp = reinterpret_cast<int4*>(featws + (size_t)(ebase - lo + wave * 16) * NPH);
        gp[lane]       = sp[lane];
        gp[lane + 64]  = sp[lane + 64];
        gp[lane + 128] = sp[lane + 128];
        if (lane < 32) gp[lane + 192] = sp[lane + 192];
    } else {
        // fallback: fused epilogue with atomics
        int sr_r[4], d_r[4]; float nm_r[4];
#pragma unroll
        for (int r = 0; r < 4; ++r) {
            int ei = ebase + wave * 16 + lk * 4 + r;
            sr_r[r] = src[ei]; d_r[r] = dst[ei]; nm_r[r] = norm[d_r[r]];
        }
#pragma unroll
        for (int nt = 0; nt < NT_O; ++nt) {
            int o = nt * 16 + lrow;
            if (o < OUT_FEAT) {
#pragma unroll
                for (int r = 0; r < 4; ++r) {
                    const float* wr = weight +
                        (size_t)((at_r[r] - attn) / (NUM_HEADS * OUT_FEAT)) * OUT_FEAT;
                    float mg = h[(size_t)sr_r[r] * IN_FEAT + o] * wr[o];
                    atomicAdd(&out[(size_t)d_r[r] * OUT_FEAT + o],
                              (mg + feat[nt][r]) * nm_r[r]);
                }
            }
        }
    }
}

// ---------------------------------------------------------------------------
// agg kernel: one wave per node; contiguous CSR edge list; per edge read feat
// row (bf16) + h[src] (x) weight[rel] rows (f32, row-coalesced); no atomics.
// ---------------------------------------------------------------------------
__global__ __launch_bounds__(256, 4) void agg_kernel(
        const unsigned short* __restrict__ featws, const int* __restrict__ offs,
        const int* __restrict__ cnt, const int* __restrict__ perm,
        const int* __restrict__ src, const int* __restrict__ rel,
        const float* __restrict__ h, const float* __restrict__ weight,
        const float* __restrict__ norm, float* __restrict__ out,
        int lo, int hi) {
    int wv = threadIdx.x >> 6, lane = threadIdx.x & 63;
    int n = blockIdx.x * 4 + wv;
    if (n >= N_NODES) return;
    int start = offs[n], deg = cnt[n];
    const int c = lane;                 // uint column: outputs 2c, 2c+1
    float ax = 0.f, ay = 0.f;
    const unsigned* fp = reinterpret_cast<const unsigned*>(featws);
    const bool act = (c < OUT_FEAT / 2);

    for (int base = 0; base < deg; base += 64) {
        int rem = deg - base; if (rem > 64) rem = 64;
        int ev = 0, sv = 0, rv = 0;
        if (lane < rem) {
            ev = perm[start + base + lane];
            sv = src[ev];
            rv = rel[ev];
        }
        int j = 0;
        for (; j + 2 <= rem; j += 2) {
            int e0 = __shfl(ev, j),     e1 = __shfl(ev, j + 1);
            int s0 = __shfl(sv, j),     s1 = __shfl(sv, j + 1);
            int r0 = __shfl(rv, j),     r1 = __shfl(rv, j + 1);
            bool in0 = (e0 >= lo && e0 < hi), in1 = (e1 >= lo && e1 < hi);
            if (act) {
                float2 h0, w0, h1, w1; unsigned f0 = 0, f1 = 0;
                if (in0) {
                    h0 = *reinterpret_cast<const float2*>(h + (size_t)s0 * IN_FEAT + 2 * c);
                    w0 = *reinterpret_cast<const float2*>(weight + (size_t)r0 * OUT_FEAT + 2 * c);
                    f0 = fp[(size_t)(e0 - lo) * (NPH / 2) + c];
                }
                if (in1) {
                    h1 = *reinterpret_cast<const float2*>(h + (size_t)s1 * IN_FEAT + 2 * c);
                    w1 = *reinterpret_cast<const float2*>(weight + (size_t)r1 * OUT_FEAT + 2 * c);
                    f1 = fp[(size_t)(e1 - lo) * (NPH / 2) + c];
                }
                if (in0) {
                    ax += h0.x * w0.x + bf2f(f0 & 0xffffu);
                    ay += h0.y * w0.y + bf2f(f0 >> 16);
                }
                if (in1) {
                    ax += h1.x * w1.x + bf2f(f1 & 0xffffu);
                    ay += h1.y * w1.y + bf2f(f1 >> 16);
                }
            }
        }
        if (j < rem) {
            int e0 = __shfl(ev, j);
            int s0 = __shfl(sv, j);
            int r0 = __shfl(rv, j);
            if (act && e0 >= lo && e0 < hi) {
                float2 h0 = *reinterpret_cast<const float2*>(h + (size_t)s0 * IN_FEAT + 2 * c);
                float2 w0 = *reinterpret_cast<const float2*>(weight + (size_t)r0 * OUT_FEAT + 2 * c);
                unsigned f0 = fp[(size_t)(e0 - lo) * (NPH / 2) + c];
                ax += h0.x * w0.x + bf2f(f0 & 0xffffu);
                ay += h0.y * w0.y + bf2f(f0 >> 16);
            }
        }
    }
    if (act && deg > 0) {
        float nm = norm[n];
        float2* op = reinterpret_cast<float2*>(out + (size_t)n * OUT_FEAT) + c;
        float2 cur = *op;
        cur.x += ax * nm; cur.y += ay * nm;
        *op = cur;
    }
}

extern "C" void kernel_launch(void* const* d_in, const int* in_sizes, int n_in,
                              void* d_out, int out_size, void* d_ws, size_t ws_size,
                              hipStream_t stream) {
    const float* h      = (const float*)d_in[0];
    const float* efeat  = (const float*)d_in[1];
    const float* norm   = (const float*)d_in[2];
    const float* weight = (const float*)d_in[3];
    const float* attn   = (const float*)d_in[4];
    const float* fc_w   = (const float*)d_in[5];
    const float* loop_w = (const float*)d_in[6];
    const int*   rel    = (const int*)d_in[7];
    const int*   src    = (const int*)d_in[8];
    const int*   dst    = (const int*)d_in[9];
    float* out = (float*)d_out;

    char* ws = (char*)d_ws;
    unsigned short* Bimg  = (unsigned short*)(ws + WS_B);
    unsigned short* LWimg = (unsigned short*)(ws + WS_LW);
    int* cnt    = (int*)(ws + WS_CNT);
    int* offs   = (int*)(ws + WS_OFFS);
    int* cursor = (int*)(ws + WS_CURSOR);
    int* bsum   = (int*)(ws + WS_BSUM);
    int* perm   = (int*)(ws + WS_PERM);
    unsigned short* featws = (unsigned short*)(ws + WS_FEAT);

    build_B<<<(NP * 16 + 255) / 256, 256, 0, stream>>>(fc_w, Bimg);
    build_LW<<<(NPH * 16 + 255) / 256, 256, 0, stream>>>(loop_w, LWimg);
    loop_gemm<<<(N_NODES + MB - 1) / MB, 512, 0, stream>>>(h, LWimg, out);

    long long avail = (long long)ws_size - (long long)WS_FEAT;
    long long rows = (avail > 0) ? avail / (NPH * 2) : 0;
    rows = (rows / MB) * MB;
    if (rows > N_EDGES) rows = N_EDGES;

    if (rows >= 100000) {
        hipMemsetAsync(cnt, 0, NNODES_PAD * sizeof(int), stream);
        hist_kernel<<<(N_EDGES + 511) / 512, 512, 0, stream>>>(dst, cnt);
        scan1<<<NNODES_PAD / 1024, 1024, 0, stream>>>(cnt, offs, bsum);
        scan2<<<1, 64, 0, stream>>>(bsum);
        scan3<<<NNODES_PAD / 1024, 1024, 0, stream>>>(offs, bsum, cursor);
        scatter_kernel<<<(N_EDGES + 511) / 512, 512, 0, stream>>>(dst, cursor, perm);

        for (long long lo = 0; lo < N_EDGES; lo += rows) {
            long long hi = lo + rows; if (hi > N_EDGES) hi = N_EDGES;
            int nb = (int)((hi - lo) / MB);
            feat_kernel<true><<<nb, 512, 0, stream>>>(
                efeat, rel, Bimg, attn, h, weight, norm, src, dst, out,
                featws, (int)lo);
            agg_kernel<<<(N_NODES + 3) / 4, 256, 0, stream>>>(
                featws, offs, cnt, perm, src, rel, h, weight, norm, out,
                (int)lo, (int)hi);
        }
    } else {
        feat_kernel<false><<<N_EDGES / MB, 512, 0, stream>>>(
            efeat, rel, Bimg, attn, h, weight, norm, src, dst, out,
            featws, 0);
    }
}

// Round 6
// 656.726 us; speedup vs baseline: 1.1852x; 1.1852x over previous
//
#include <hip/hip_runtime.h>
#include <hip/hip_bf16.h>

#define N_NODES 50000
#define N_EDGES 800000
#define IN_FEAT 100
#define OUT_FEAT 100
#define NUM_RELS 200
#define NUM_HEADS 3

#define KP 128          // padded K (100 -> 128)
#define NPH 112         // per-head padded N (100 -> 112 = 7*16)
#define NP  336         // 3 * 112
#define MB  128         // edges (or node-rows) per block for non-persistent kernels
#define NT_O 7          // NPH/16
#define TPW 1792        // ushorts of featws per 16-edge tile (16*112)

// ---- workspace layout (bytes) ----
#define WS_B       0u           // fc_w^T bf16 image, per-head swizzled: 86016
#define WS_LW      86016u       // loop_w^T bf16 image (linear): 28672
#define WS_CNT     114688u      // 50176 ints
#define WS_OFFS    315392u
#define WS_CURSOR  516096u
#define WS_BSUM    716800u      // 64 ints
#define WS_PERM    717056u      // 800000 ints
#define WS_FEAT    3917056u     // bf16 feat tiles, MFMA-native layout, 1792 ushorts/tile
#define NNODES_PAD 50176        // 49*1024

typedef __attribute__((ext_vector_type(8))) short short8;
typedef __attribute__((ext_vector_type(4))) float f32x4;

__device__ __forceinline__ unsigned short f2bf(float f) {
    unsigned u = __builtin_bit_cast(unsigned, f);
    unsigned r = u + 0x7FFFu + ((u >> 16) & 1u);
    return (unsigned short)(r >> 16);
}
__device__ __forceinline__ float bf2f(unsigned hs) {
    return __builtin_bit_cast(float, hs << 16);
}

// ---------------------------------------------------------------------------
// B = fc_w^T bf16, per-head regions, XOR-swizzled (round-4 layout, proven):
// granule g of row (head,nl) at byte  head*28672 + nl*256 + ((g*16) ^ ((nl&7)<<4))
// granule content: elem j in [0,8): k = kt*32 + (j>>2)*16 + g4*4 + (j&3)
// ---------------------------------------------------------------------------
__global__ __launch_bounds__(256) void build_B(const float* __restrict__ fc_w,
                                               unsigned short* __restrict__ Bws) {
    int idx = blockIdx.x * 256 + threadIdx.x;     // granule id: n*16 + g
    if (idx >= NP * 16) return;
    int n = idx >> 4, g = idx & 15;
    int head = n / NPH, nl = n - head * NPH;
    int kt = g >> 2, g4 = g & 3;
    unsigned p[4];
#pragma unroll
    for (int half = 0; half < 2; ++half) {
#pragma unroll
        for (int jp = 0; jp < 2; ++jp) {
            int k_lo = kt * 32 + half * 16 + g4 * 4 + jp * 2;
            int k_hi = k_lo + 1;
            float vlo = (k_lo < IN_FEAT && nl < OUT_FEAT)
                      ? fc_w[k_lo * (OUT_FEAT * NUM_HEADS) + head * OUT_FEAT + nl] : 0.f;
            float vhi = (k_hi < IN_FEAT && nl < OUT_FEAT)
                      ? fc_w[k_hi * (OUT_FEAT * NUM_HEADS) + head * OUT_FEAT + nl] : 0.f;
            p[half * 2 + jp] = (unsigned)f2bf(vlo) | ((unsigned)f2bf(vhi) << 16);
        }
    }
    unsigned off = (unsigned)(head * (NPH * KP * 2)) +
                   (((unsigned)(nl * (KP * 2) + g * 16)) ^ (((unsigned)(nl & 7)) << 4));
    *reinterpret_cast<int4*>(reinterpret_cast<char*>(Bws) + off) =
        make_int4((int)p[0], (int)p[1], (int)p[2], (int)p[3]);
}

// loop_w^T bf16 image, LINEAR (read from L2 by loop_gemm fragments)
__global__ __launch_bounds__(256) void build_LW(const float* __restrict__ loop_w,
                                                unsigned short* __restrict__ LWws) {
    int idx = blockIdx.x * 256 + threadIdx.x;
    if (idx >= NPH * 16) return;
    int nl = idx >> 4, g = idx & 15;
    int kt = g >> 2, g4 = g & 3;
    unsigned p[4];
#pragma unroll
    for (int half = 0; half < 2; ++half) {
#pragma unroll
        for (int jp = 0; jp < 2; ++jp) {
            int k_lo = kt * 32 + half * 16 + g4 * 4 + jp * 2;
            int k_hi = k_lo + 1;
            float vlo = (k_lo < IN_FEAT && nl < OUT_FEAT) ? loop_w[k_lo * OUT_FEAT + nl] : 0.f;
            float vhi = (k_hi < IN_FEAT && nl < OUT_FEAT) ? loop_w[k_hi * OUT_FEAT + nl] : 0.f;
            p[half * 2 + jp] = (unsigned)f2bf(vlo) | ((unsigned)f2bf(vhi) << 16);
        }
    }
    reinterpret_cast<int4*>(LWws)[idx] = make_int4((int)p[0], (int)p[1], (int)p[2], (int)p[3]);
}

// ---------------------------------------------------------------------------
// Self-loop GEMM: out = h @ loop_w. Zero LDS/barriers; LW from L2. (round-5)
// ---------------------------------------------------------------------------
__global__ __launch_bounds__(512, 2) void loop_gemm(const float* __restrict__ h,
                                                    const unsigned short* __restrict__ LWimg,
                                                    float* __restrict__ out) {
    const int tid = threadIdx.x;
    const int wave = tid >> 6, lane = tid & 63;
    const int lrow = lane & 15, lk = lane >> 4;
    const int rbase = blockIdx.x * MB;
    const int grow = rbase + wave * 16 + lrow;
    const bool ok = grow < N_NODES;
    const float* ap = h + (size_t)grow * IN_FEAT;

    short8 afrag[4];
#pragma unroll
    for (int kt = 0; kt < 4; ++kt) {
        int k0 = kt * 32 + lk * 4, k1 = k0 + 16;
        float4 va = (ok && k0 + 4 <= IN_FEAT) ? *reinterpret_cast<const float4*>(ap + k0)
                                              : make_float4(0.f, 0.f, 0.f, 0.f);
        float4 vb = (ok && k1 + 4 <= IN_FEAT) ? *reinterpret_cast<const float4*>(ap + k1)
                                              : make_float4(0.f, 0.f, 0.f, 0.f);
        afrag[kt][0] = (short)f2bf(va.x); afrag[kt][1] = (short)f2bf(va.y);
        afrag[kt][2] = (short)f2bf(va.z); afrag[kt][3] = (short)f2bf(va.w);
        afrag[kt][4] = (short)f2bf(vb.x); afrag[kt][5] = (short)f2bf(vb.y);
        afrag[kt][6] = (short)f2bf(vb.z); afrag[kt][7] = (short)f2bf(vb.w);
    }

#pragma unroll
    for (int nt = 0; nt < NT_O; ++nt) {
        f32x4 acc = (f32x4){0.f, 0.f, 0.f, 0.f};
#pragma unroll
        for (int kt = 0; kt < 4; ++kt) {
            short8 bfrag = *reinterpret_cast<const short8*>(
                LWimg + ((nt * 16 + lrow) * KP + kt * 32 + lk * 8));
            acc = __builtin_amdgcn_mfma_f32_16x16x32_bf16(afrag[kt], bfrag, acc, 0, 0, 0);
        }
        int o = nt * 16 + lrow;
        if (o < OUT_FEAT) {
#pragma unroll
            for (int r = 0; r < 4; ++r) {
                int crow = rbase + wave * 16 + lk * 4 + r;
                if (crow < N_NODES) out[(size_t)crow * OUT_FEAT + o] = acc[r];
            }
        }
    }
}

// ---------------------------------------------------------------------------
// CSR construction
// ---------------------------------------------------------------------------
__global__ __launch_bounds__(512) void hist_kernel(const int* __restrict__ dst,
                                                   int* __restrict__ cnt) {
    int e = blockIdx.x * 512 + threadIdx.x;
    if (e < N_EDGES) atomicAdd(&cnt[dst[e]], 1);
}

__global__ __launch_bounds__(1024) void scan1(const int* __restrict__ cnt,
                                              int* __restrict__ offs,
                                              int* __restrict__ bsum) {
    __shared__ int s[1024];
    int i = blockIdx.x * 1024 + threadIdx.x;
    int v = (i < N_NODES) ? cnt[i] : 0;
    s[threadIdx.x] = v;
    __syncthreads();
    for (int d = 1; d < 1024; d <<= 1) {
        int t = (threadIdx.x >= d) ? s[threadIdx.x - d] : 0;
        __syncthreads();
        s[threadIdx.x] += t;
        __syncthreads();
    }
    offs[i] = s[threadIdx.x] - v;
    if (threadIdx.x == 1023) bsum[blockIdx.x] = s[1023];
}

__global__ __launch_bounds__(64) void scan2(int* __restrict__ bsum) {
    __shared__ int s[64];
    int v = (threadIdx.x < NNODES_PAD / 1024) ? bsum[threadIdx.x] : 0;
    s[threadIdx.x] = v;
    __syncthreads();
    for (int d = 1; d < 64; d <<= 1) {
        int t = (threadIdx.x >= d) ? s[threadIdx.x - d] : 0;
        __syncthreads();
        s[threadIdx.x] += t;
        __syncthreads();
    }
    bsum[threadIdx.x] = s[threadIdx.x] - v;
}

__global__ __launch_bounds__(1024) void scan3(int* __restrict__ offs,
                                              const int* __restrict__ bsum,
                                              int* __restrict__ cursor) {
    int i = blockIdx.x * 1024 + threadIdx.x;
    int v = offs[i] + bsum[blockIdx.x];
    offs[i] = v;
    cursor[i] = v;
}

__global__ __launch_bounds__(512) void scatter_kernel(const int* __restrict__ dst,
                                                      int* __restrict__ cursor,
                                                      int* __restrict__ perm) {
    int e = blockIdx.x * 512 + threadIdx.x;
    if (e < N_EDGES) {
        int p = atomicAdd(&cursor[dst[e]], 1);
        perm[p] = e;
    }
}

// ---------------------------------------------------------------------------
// feat kernel v6: persistent full-B in LDS (86 KB, staged once, ONE barrier),
// 16 waves grid-stride over 16-edge tiles, A prefetched into registers,
// feat written in MFMA-native layout (7 coalesced ushort4 stores, no LDS).
// LDS pins 1 block/CU -> compiler targets 4 waves/SIMD -> full 128-VGPR alloc.
// ---------------------------------------------------------------------------
template<bool TOWS>
__global__ __launch_bounds__(1024, 4) void feat_kernel(
        const float* __restrict__ efeat, const int* __restrict__ rel,
        const unsigned short* __restrict__ Bimg, const float* __restrict__ attn,
        const float* __restrict__ h, const float* __restrict__ weight,
        const float* __restrict__ norm, const int* __restrict__ src,
        const int* __restrict__ dst, float* __restrict__ out,
        unsigned short* __restrict__ featws, int lo, int ntiles) {

    __shared__ unsigned short Blds[NP * KP];   // 86016 B, swizzled (linear copy)

    const int tid = threadIdx.x;
    {
        const int4* sp = reinterpret_cast<const int4*>(Bimg);
        int4* dp = reinterpret_cast<int4*>(Blds);
        for (int i = tid; i < NP * KP / 8; i += 1024) dp[i] = sp[i];
    }
    __syncthreads();   // the only barrier in this kernel

    const int wave = tid >> 6, lane = tid & 63;
    const int lrow = lane & 15, lk = lane >> 4;
    const int gstride = gridDim.x * 16;
    int tile = blockIdx.x * 16 + wave;
    if (tile >= ntiles) return;

    // lane-constant swizzled LDS base per kt; full address = base + hh*28672 + nt*4096
    const char* Bc = reinterpret_cast<const char*>(Blds);
    int bkt[4];
#pragma unroll
    for (int kt = 0; kt < 4; ++kt)
        bkt[kt] = lrow * (KP * 2) + ((kt * 64 + lk * 16) ^ ((lrow & 7) << 4));

    // ---- preload first tile's A + rel ----
    float4 pa[8];
    int rl[4];
    {
        const float* ap = efeat + (size_t)(lo + tile * 16 + lrow) * IN_FEAT;
#pragma unroll
        for (int kt = 0; kt < 4; ++kt) {
            int k0 = kt * 32 + lk * 4, k1 = k0 + 16;
            pa[kt * 2]     = (k0 + 4 <= IN_FEAT) ? *reinterpret_cast<const float4*>(ap + k0)
                                                 : make_float4(0.f, 0.f, 0.f, 0.f);
            pa[kt * 2 + 1] = (k1 + 4 <= IN_FEAT) ? *reinterpret_cast<const float4*>(ap + k1)
                                                 : make_float4(0.f, 0.f, 0.f, 0.f);
        }
        const int* rp = rel + lo + tile * 16 + lk * 4;
#pragma unroll
        for (int r = 0; r < 4; ++r) rl[r] = rp[r];
    }

    while (true) {
        const int cur = tile;
        // ---- consume A into fragments ----
        short8 afrag[4];
#pragma unroll
        for (int kt = 0; kt < 4; ++kt) {
            float4 va = pa[kt * 2], vb = pa[kt * 2 + 1];
            afrag[kt][0] = (short)f2bf(va.x); afrag[kt][1] = (short)f2bf(va.y);
            afrag[kt][2] = (short)f2bf(va.z); afrag[kt][3] = (short)f2bf(va.w);
            afrag[kt][4] = (short)f2bf(vb.x); afrag[kt][5] = (short)f2bf(vb.y);
            afrag[kt][6] = (short)f2bf(vb.z); afrag[kt][7] = (short)f2bf(vb.w);
        }
        // per-row attn offsets (and fallback metadata) BEFORE prefetch clobbers rl
        int aoffv[4];
#pragma unroll
        for (int r = 0; r < 4; ++r) aoffv[r] = rl[r] * (NUM_HEADS * OUT_FEAT);
        int sr_r[4], d_r[4]; float nm_r[4]; const float* wr_r[4];
        if (!TOWS) {
#pragma unroll
            for (int r = 0; r < 4; ++r) {
                int ei = lo + cur * 16 + lk * 4 + r;
                sr_r[r] = src[ei]; d_r[r] = dst[ei]; nm_r[r] = norm[d_r[r]];
                wr_r[r] = weight + (size_t)rl[r] * OUT_FEAT;
            }
        }

        // ---- issue next tile's A + rel prefetch ----
        int next = tile + gstride;
        bool more = next < ntiles;
        {
            int pidx = more ? next : cur;
            const float* ap = efeat + (size_t)(lo + pidx * 16 + lrow) * IN_FEAT;
#pragma unroll
            for (int kt = 0; kt < 4; ++kt) {
                int k0 = kt * 32 + lk * 4, k1 = k0 + 16;
                pa[kt * 2]     = (k0 + 4 <= IN_FEAT) ? *reinterpret_cast<const float4*>(ap + k0)
                                                     : make_float4(0.f, 0.f, 0.f, 0.f);
                pa[kt * 2 + 1] = (k1 + 4 <= IN_FEAT) ? *reinterpret_cast<const float4*>(ap + k1)
                                                     : make_float4(0.f, 0.f, 0.f, 0.f);
            }
            const int* rp = rel + lo + pidx * 16 + lk * 4;
#pragma unroll
            for (int r = 0; r < 4; ++r) rl[r] = rp[r];
        }

        // ---- 3 heads x 7 col-tiles x K=128, B from LDS (imm-offset addressed) ----
        float feat[NT_O][4];
#pragma unroll
        for (int nt = 0; nt < NT_O; ++nt)
#pragma unroll
            for (int r = 0; r < 4; ++r) feat[nt][r] = 0.f;

#pragma unroll 1
        for (int hh = 0; hh < NUM_HEADS; ++hh) {
            const char* Bh = Bc + hh * (NPH * KP * 2);
#pragma unroll
            for (int nt = 0; nt < NT_O; ++nt) {
                f32x4 acc = (f32x4){0.f, 0.f, 0.f, 0.f};
#pragma unroll
                for (int kt = 0; kt < 4; ++kt) {
                    short8 bfrag = *reinterpret_cast<const short8*>(
                        Bh + bkt[kt] + nt * 4096);
                    acc = __builtin_amdgcn_mfma_f32_16x16x32_bf16(afrag[kt], bfrag, acc, 0, 0, 0);
                }
                int o = nt * 16 + lrow;
                if (o < OUT_FEAT) {
                    int oo = hh * OUT_FEAT + o;
#pragma unroll
                    for (int r = 0; r < 4; ++r) {
                        float v = acc[r] * attn[aoffv[r] + oo];
                        feat[nt][r] += (v > 0.f) ? v : 0.2f * v;
                    }
                }
            }
        }

        if (TOWS) {
            // MFMA-native layout: per nt, lane stores its 4 bf16 at idx
            // tile*1792 + nt*256 + lane*4  (64 lanes -> 512 B contiguous)
            unsigned short* gp = featws + (size_t)cur * TPW + lane * 4;
#pragma unroll
            for (int nt = 0; nt < NT_O; ++nt) {
                ushort4 v;
                v.x = f2bf(feat[nt][0]); v.y = f2bf(feat[nt][1]);
                v.z = f2bf(feat[nt][2]); v.w = f2bf(feat[nt][3]);
                *reinterpret_cast<ushort4*>(gp + nt * 256) = v;
            }
        } else {
#pragma unroll
            for (int nt = 0; nt < NT_O; ++nt) {
                int o = nt * 16 + lrow;
                if (o < OUT_FEAT) {
#pragma unroll
                    for (int r = 0; r < 4; ++r) {
                        float mg = h[(size_t)sr_r[r] * IN_FEAT + o] * wr_r[r][o];
                        atomicAdd(&out[(size_t)d_r[r] * OUT_FEAT + o],
                                  (mg + feat[nt][r]) * nm_r[r]);
                    }
                }
            }
        }

        if (!more) break;
        tile = next;
    }
}

// ---------------------------------------------------------------------------
// agg kernel: one wave per node; CSR gather; feat read from MFMA-native layout
// (element (edge el, col o) at tile*1792 + (o>>4)*256 + (el>>2)*64 + (o&15)*4 + (el&3))
// ---------------------------------------------------------------------------
__global__ __launch_bounds__(256, 4) void agg_kernel(
        const unsigned short* __restrict__ featws, const int* __restrict__ offs,
        const int* __restrict__ cnt, const int* __restrict__ perm,
        const int* __restrict__ src, const int* __restrict__ rel,
        const float* __restrict__ h, const float* __restrict__ weight,
        const float* __restrict__ norm, float* __restrict__ out,
        int lo, int hi) {
    int wv = threadIdx.x >> 6, lane = threadIdx.x & 63;
    int n = blockIdx.x * 4 + wv;
    if (n >= N_NODES) return;
    int start = offs[n], deg = cnt[n];
    const int c = lane;                 // column pair: outputs 2c, 2c+1
    float ax = 0.f, ay = 0.f;
    const bool act = (c < OUT_FEAT / 2);
    // lane-constant part of the feat index for cols 2c (and 2c+1 = +4)
    const int coff = ((2 * c) >> 4) * 256 + ((2 * c) & 15) * 4;

    for (int base = 0; base < deg; base += 64) {
        int rem = deg - base; if (rem > 64) rem = 64;
        int ev = 0, sv = 0, rv = 0;
        if (lane < rem) {
            ev = perm[start + base + lane];
            sv = src[ev];
            rv = rel[ev];
        }
#pragma unroll 1
        for (int j = 0; j < rem; ++j) {
            int e = __shfl(ev, j);
            if (e < lo || e >= hi) continue;          // wave-uniform
            int s = __shfl(sv, j);
            int rL = __shfl(rv, j);
            if (act) {
                int el = (e - lo) & 15;
                size_t fb = (size_t)((e - lo) >> 4) * TPW + (el >> 2) * 64 + (el & 3) + coff;
                float2 h2 = *reinterpret_cast<const float2*>(h + (size_t)s * IN_FEAT + 2 * c);
                float2 w2 = *reinterpret_cast<const float2*>(weight + (size_t)rL * OUT_FEAT + 2 * c);
                float f0 = bf2f(featws[fb]);
                float f1 = bf2f(featws[fb + 4]);
                ax += h2.x * w2.x + f0;
                ay += h2.y * w2.y + f1;
            }
        }
    }
    if (act && deg > 0) {
        float nm = norm[n];
        float2* op = reinterpret_cast<float2*>(out + (size_t)n * OUT_FEAT) + c;
        float2 cur = *op;
        cur.x += ax * nm; cur.y += ay * nm;
        *op = cur;
    }
}

extern "C" void kernel_launch(void* const* d_in, const int* in_sizes, int n_in,
                              void* d_out, int out_size, void* d_ws, size_t ws_size,
                              hipStream_t stream) {
    const float* h      = (const float*)d_in[0];
    const float* efeat  = (const float*)d_in[1];
    const float* norm   = (const float*)d_in[2];
    const float* weight = (const float*)d_in[3];
    const float* attn   = (const float*)d_in[4];
    const float* fc_w   = (const float*)d_in[5];
    const float* loop_w = (const float*)d_in[6];
    const int*   rel    = (const int*)d_in[7];
    const int*   src    = (const int*)d_in[8];
    const int*   dst    = (const int*)d_in[9];
    float* out = (float*)d_out;

    char* ws = (char*)d_ws;
    unsigned short* Bimg  = (unsigned short*)(ws + WS_B);
    unsigned short* LWimg = (unsigned short*)(ws + WS_LW);
    int* cnt    = (int*)(ws + WS_CNT);
    int* offs   = (int*)(ws + WS_OFFS);
    int* cursor = (int*)(ws + WS_CURSOR);
    int* bsum   = (int*)(ws + WS_BSUM);
    int* perm   = (int*)(ws + WS_PERM);
    unsigned short* featws = (unsigned short*)(ws + WS_FEAT);

    build_B<<<(NP * 16 + 255) / 256, 256, 0, stream>>>(fc_w, Bimg);
    build_LW<<<(NPH * 16 + 255) / 256, 256, 0, stream>>>(loop_w, LWimg);
    loop_gemm<<<(N_NODES + MB - 1) / MB, 512, 0, stream>>>(h, LWimg, out);

    long long avail = (long long)ws_size - (long long)WS_FEAT;
    long long rows = (avail > 0) ? avail / (NPH * 2) : 0;
    rows = (rows / MB) * MB;
    if (rows > N_EDGES) rows = N_EDGES;

    if (rows >= 100000) {
        hipMemsetAsync(cnt, 0, NNODES_PAD * sizeof(int), stream);
        hist_kernel<<<(N_EDGES + 511) / 512, 512, 0, stream>>>(dst, cnt);
        scan1<<<NNODES_PAD / 1024, 1024, 0, stream>>>(cnt, offs, bsum);
        scan2<<<1, 64, 0, stream>>>(bsum);
        scan3<<<NNODES_PAD / 1024, 1024, 0, stream>>>(offs, bsum, cursor);
        scatter_kernel<<<(N_EDGES + 511) / 512, 512, 0, stream>>>(dst, cursor, perm);

        for (long long lo = 0; lo < N_EDGES; lo += rows) {
            long long hi = lo + rows; if (hi > N_EDGES) hi = N_EDGES;
            int ntiles = (int)((hi - lo) / 16);
            int nb = (ntiles + 15) / 16; if (nb > 256) nb = 256;
            feat_kernel<true><<<nb, 1024, 0, stream>>>(
                efeat, rel, Bimg, attn, h, weight, norm, src, dst, out,
                featws, (int)lo, ntiles);
            agg_kernel<<<(N_NODES + 3) / 4, 256, 0, stream>>>(
                featws, offs, cnt, perm, src, rel, h, weight, norm, out,
                (int)lo, (int)hi);
        }
    } else {
        feat_kernel<false><<<(N_EDGES / 16 + 255) / 256, 1024, 0, stream>>>(
            efeat, rel, Bimg, attn, h, weight, norm, src, dst, out,
            featws, 0, N_EDGES / 16);
    }
}

// Round 7
// 493.647 us; speedup vs baseline: 1.5768x; 1.3304x over previous
//
#include <hip/hip_runtime.h>
#include <hip/hip_bf16.h>

#define N_NODES 50000
#define N_EDGES 800000
#define IN_FEAT 100
#define OUT_FEAT 100
#define NUM_RELS 200
#define NUM_HEADS 3

#define KP 128          // padded K (100 -> 128)
#define NPH 112         // per-head padded N (100 -> 112 = 7*16)
#define NP  336         // 3 * 112
#define MB  128         // node-rows per block (loop_gemm)
#define NT_O 7          // NPH/16
#define WPB 12          // waves per feat block (768 threads)

// ---- workspace layout (bytes) ----
#define WS_B       0u           // fc_w^T bf16 image, per-head swizzled: 86016
#define WS_LW      86016u       // loop_w^T bf16 image (linear): 28672
#define WS_CNT     114688u      // 50176 ints
#define WS_OFFS    315392u
#define WS_CURSOR  516096u
#define WS_BSUM    716800u      // 64 ints
#define WS_PERM    717056u      // 800000 ints
#define WS_MSG     3917056u     // bf16 msg rows (112 ushorts = 224 B each), perm order
#define NNODES_PAD 50176        // 49*1024

typedef __attribute__((ext_vector_type(8))) short short8;
typedef __attribute__((ext_vector_type(4))) float f32x4;

__device__ __forceinline__ unsigned short f2bf(float f) {
    unsigned u = __builtin_bit_cast(unsigned, f);
    unsigned r = u + 0x7FFFu + ((u >> 16) & 1u);
    return (unsigned short)(r >> 16);
}
__device__ __forceinline__ float bf2f(unsigned hs) {
    return __builtin_bit_cast(float, hs << 16);
}

// ---------------------------------------------------------------------------
// B = fc_w^T bf16, per-head regions, XOR-swizzled (proven layout):
// granule g of row (head,nl) at byte  head*28672 + nl*256 + ((g*16) ^ ((nl&7)<<4))
// granule elem j in [0,8): k = kt*32 + (j>>2)*16 + g4*4 + (j&3)
// ---------------------------------------------------------------------------
__global__ __launch_bounds__(256) void build_B(const float* __restrict__ fc_w,
                                               unsigned short* __restrict__ Bws) {
    int idx = blockIdx.x * 256 + threadIdx.x;     // granule id: n*16 + g
    if (idx >= NP * 16) return;
    int n = idx >> 4, g = idx & 15;
    int head = n / NPH, nl = n - head * NPH;
    int kt = g >> 2, g4 = g & 3;
    unsigned p[4];
#pragma unroll
    for (int half = 0; half < 2; ++half) {
#pragma unroll
        for (int jp = 0; jp < 2; ++jp) {
            int k_lo = kt * 32 + half * 16 + g4 * 4 + jp * 2;
            int k_hi = k_lo + 1;
            float vlo = (k_lo < IN_FEAT && nl < OUT_FEAT)
                      ? fc_w[k_lo * (OUT_FEAT * NUM_HEADS) + head * OUT_FEAT + nl] : 0.f;
            float vhi = (k_hi < IN_FEAT && nl < OUT_FEAT)
                      ? fc_w[k_hi * (OUT_FEAT * NUM_HEADS) + head * OUT_FEAT + nl] : 0.f;
            p[half * 2 + jp] = (unsigned)f2bf(vlo) | ((unsigned)f2bf(vhi) << 16);
        }
    }
    unsigned off = (unsigned)(head * (NPH * KP * 2)) +
                   (((unsigned)(nl * (KP * 2) + g * 16)) ^ (((unsigned)(nl & 7)) << 4));
    *reinterpret_cast<int4*>(reinterpret_cast<char*>(Bws) + off) =
        make_int4((int)p[0], (int)p[1], (int)p[2], (int)p[3]);
}

// loop_w^T bf16 image, LINEAR (read from L2 by loop_gemm fragments)
__global__ __launch_bounds__(256) void build_LW(const float* __restrict__ loop_w,
                                                unsigned short* __restrict__ LWws) {
    int idx = blockIdx.x * 256 + threadIdx.x;
    if (idx >= NPH * 16) return;
    int nl = idx >> 4, g = idx & 15;
    int kt = g >> 2, g4 = g & 3;
    unsigned p[4];
#pragma unroll
    for (int half = 0; half < 2; ++half) {
#pragma unroll
        for (int jp = 0; jp < 2; ++jp) {
            int k_lo = kt * 32 + half * 16 + g4 * 4 + jp * 2;
            int k_hi = k_lo + 1;
            float vlo = (k_lo < IN_FEAT && nl < OUT_FEAT) ? loop_w[k_lo * OUT_FEAT + nl] : 0.f;
            float vhi = (k_hi < IN_FEAT && nl < OUT_FEAT) ? loop_w[k_hi * OUT_FEAT + nl] : 0.f;
            p[half * 2 + jp] = (unsigned)f2bf(vlo) | ((unsigned)f2bf(vhi) << 16);
        }
    }
    reinterpret_cast<int4*>(LWws)[idx] = make_int4((int)p[0], (int)p[1], (int)p[2], (int)p[3]);
}

// ---------------------------------------------------------------------------
// Self-loop GEMM: out = h @ loop_w. Zero LDS/barriers; LW from L2.
// ---------------------------------------------------------------------------
__global__ __launch_bounds__(512, 2) void loop_gemm(const float* __restrict__ h,
                                                    const unsigned short* __restrict__ LWimg,
                                                    float* __restrict__ out) {
    const int tid = threadIdx.x;
    const int wave = tid >> 6, lane = tid & 63;
    const int lrow = lane & 15, lk = lane >> 4;
    const int rbase = blockIdx.x * MB;
    const int grow = rbase + wave * 16 + lrow;
    const bool ok = grow < N_NODES;
    const float* ap = h + (size_t)grow * IN_FEAT;

    short8 afrag[4];
#pragma unroll
    for (int kt = 0; kt < 4; ++kt) {
        int k0 = kt * 32 + lk * 4, k1 = k0 + 16;
        float4 va = (ok && k0 + 4 <= IN_FEAT) ? *reinterpret_cast<const float4*>(ap + k0)
                                              : make_float4(0.f, 0.f, 0.f, 0.f);
        float4 vb = (ok && k1 + 4 <= IN_FEAT) ? *reinterpret_cast<const float4*>(ap + k1)
                                              : make_float4(0.f, 0.f, 0.f, 0.f);
        afrag[kt][0] = (short)f2bf(va.x); afrag[kt][1] = (short)f2bf(va.y);
        afrag[kt][2] = (short)f2bf(va.z); afrag[kt][3] = (short)f2bf(va.w);
        afrag[kt][4] = (short)f2bf(vb.x); afrag[kt][5] = (short)f2bf(vb.y);
        afrag[kt][6] = (short)f2bf(vb.z); afrag[kt][7] = (short)f2bf(vb.w);
    }

#pragma unroll
    for (int nt = 0; nt < NT_O; ++nt) {
        f32x4 acc = (f32x4){0.f, 0.f, 0.f, 0.f};
#pragma unroll
        for (int kt = 0; kt < 4; ++kt) {
            short8 bfrag = *reinterpret_cast<const short8*>(
                LWimg + ((nt * 16 + lrow) * KP + kt * 32 + lk * 8));
            acc = __builtin_amdgcn_mfma_f32_16x16x32_bf16(afrag[kt], bfrag, acc, 0, 0, 0);
        }
        int o = nt * 16 + lrow;
        if (o < OUT_FEAT) {
#pragma unroll
            for (int r = 0; r < 4; ++r) {
                int crow = rbase + wave * 16 + lk * 4 + r;
                if (crow < N_NODES) out[(size_t)crow * OUT_FEAT + o] = acc[r];
            }
        }
    }
}

// ---------------------------------------------------------------------------
// CSR construction
// ---------------------------------------------------------------------------
__global__ __launch_bounds__(512) void hist_kernel(const int* __restrict__ dst,
                                                   int* __restrict__ cnt) {
    int e = blockIdx.x * 512 + threadIdx.x;
    if (e < N_EDGES) atomicAdd(&cnt[dst[e]], 1);
}

__global__ __launch_bounds__(1024) void scan1(const int* __restrict__ cnt,
                                              int* __restrict__ offs,
                                              int* __restrict__ bsum) {
    __shared__ int s[1024];
    int i = blockIdx.x * 1024 + threadIdx.x;
    int v = (i < N_NODES) ? cnt[i] : 0;
    s[threadIdx.x] = v;
    __syncthreads();
    for (int d = 1; d < 1024; d <<= 1) {
        int t = (threadIdx.x >= d) ? s[threadIdx.x - d] : 0;
        __syncthreads();
        s[threadIdx.x] += t;
        __syncthreads();
    }
    offs[i] = s[threadIdx.x] - v;
    if (threadIdx.x == 1023) bsum[blockIdx.x] = s[1023];
}

__global__ __launch_bounds__(64) void scan2(int* __restrict__ bsum) {
    __shared__ int s[64];
    int v = (threadIdx.x < NNODES_PAD / 1024) ? bsum[threadIdx.x] : 0;
    s[threadIdx.x] = v;
    __syncthreads();
    for (int d = 1; d < 64; d <<= 1) {
        int t = (threadIdx.x >= d) ? s[threadIdx.x - d] : 0;
        __syncthreads();
        s[threadIdx.x] += t;
        __syncthreads();
    }
    bsum[threadIdx.x] = s[threadIdx.x] - v;
}

__global__ __launch_bounds__(1024) void scan3(int* __restrict__ offs,
                                              const int* __restrict__ bsum,
                                              int* __restrict__ cursor) {
    int i = blockIdx.x * 1024 + threadIdx.x;
    int v = offs[i] + bsum[blockIdx.x];
    offs[i] = v;
    cursor[i] = v;
}

__global__ __launch_bounds__(512) void scatter_kernel(const int* __restrict__ dst,
                                                      int* __restrict__ cursor,
                                                      int* __restrict__ perm) {
    int e = blockIdx.x * 512 + threadIdx.x;
    if (e < N_EDGES) {
        int p = atomicAdd(&cursor[dst[e]], 1);
        perm[p] = e;
    }
}

// ---------------------------------------------------------------------------
// feat kernel v7: persistent full-B LDS (one barrier), 12 waves grid-stride
// over perm-ordered 16-edge tiles; A + metadata prefetched one tile ahead;
// feat initialized with h[src]*w[rel] (gathers hidden under MFMA);
// full message (h*w + attfeat)*norm written bf16 row-major at perm slots.
// amdgpu_waves_per_eu(3,3): VGPR cap 170, compiler won't starve to 64.
// ---------------------------------------------------------------------------
template<bool TOWS>
__global__ __launch_bounds__(768)
__attribute__((amdgpu_waves_per_eu(3, 3)))
void feat_kernel(
        const float* __restrict__ efeat, const int* __restrict__ rel,
        const unsigned short* __restrict__ Bimg, const float* __restrict__ attn,
        const float* __restrict__ h, const float* __restrict__ weight,
        const float* __restrict__ norm, const int* __restrict__ src,
        const int* __restrict__ dst, const int* __restrict__ perm,
        float* __restrict__ out, unsigned short* __restrict__ msgws,
        int lo, int ntiles) {

    __shared__ unsigned short Blds[NP * KP];          // 86016 B
    __shared__ unsigned short slice[WPB][16 * NPH];   // 43008 B

    const int tid = threadIdx.x;
    {
        const int4* sp = reinterpret_cast<const int4*>(Bimg);
        int4* dp = reinterpret_cast<int4*>(Blds);
        for (int i = tid; i < NP * KP / 8; i += 768) dp[i] = sp[i];
    }
    __syncthreads();   // the only barrier

    const int wave = tid >> 6, lane = tid & 63;
    const int lrow = lane & 15, lk = lane >> 4;
    const int gstride = gridDim.x * WPB;
    int tile = blockIdx.x * WPB + wave;
    if (tile >= ntiles) return;

    const char* Bc = reinterpret_cast<const char*>(Blds);
    int bkt[4];
#pragma unroll
    for (int kt = 0; kt < 4; ++kt)
        bkt[kt] = lrow * (KP * 2) + ((kt * 64 + lk * 16) ^ ((lrow & 7) << 4));

    // ---- prefetch state for tile ----
    float4 pa[8];
    int rl[4], sr[4], dd[4];
    {
        int slot = lo + tile * 16;
        int pe = TOWS ? perm[slot + lrow] : (slot + lrow);
        const float* ap = efeat + (size_t)pe * IN_FEAT;
#pragma unroll
        for (int kt = 0; kt < 4; ++kt) {
            int k0 = kt * 32 + lk * 4, k1 = k0 + 16;
            pa[kt * 2]     = (k0 + 4 <= IN_FEAT) ? *reinterpret_cast<const float4*>(ap + k0)
                                                 : make_float4(0.f, 0.f, 0.f, 0.f);
            pa[kt * 2 + 1] = (k1 + 4 <= IN_FEAT) ? *reinterpret_cast<const float4*>(ap + k1)
                                                 : make_float4(0.f, 0.f, 0.f, 0.f);
        }
#pragma unroll
        for (int r = 0; r < 4; ++r) {
            int pr = TOWS ? perm[slot + lk * 4 + r] : (slot + lk * 4 + r);
            rl[r] = rel[pr]; sr[r] = src[pr]; dd[r] = dst[pr];
        }
    }

    while (true) {
        const int cur = tile;
        // ---- consume A into fragments ----
        short8 afrag[4];
#pragma unroll
        for (int kt = 0; kt < 4; ++kt) {
            float4 va = pa[kt * 2], vb = pa[kt * 2 + 1];
            afrag[kt][0] = (short)f2bf(va.x); afrag[kt][1] = (short)f2bf(va.y);
            afrag[kt][2] = (short)f2bf(va.z); afrag[kt][3] = (short)f2bf(va.w);
            afrag[kt][4] = (short)f2bf(vb.x); afrag[kt][5] = (short)f2bf(vb.y);
            afrag[kt][6] = (short)f2bf(vb.z); afrag[kt][7] = (short)f2bf(vb.w);
        }
        // ---- current-tile metadata (read prefetched regs BEFORE refill) ----
        float nm[4]; int aoff[4]; const float* hp[4]; const float* wp[4]; int ddc[4];
#pragma unroll
        for (int r = 0; r < 4; ++r) {
            nm[r]  = norm[dd[r]];
            aoff[r] = rl[r] * (NUM_HEADS * OUT_FEAT);
            hp[r]  = h + (size_t)sr[r] * IN_FEAT;
            wp[r]  = weight + (size_t)rl[r] * OUT_FEAT;
            ddc[r] = dd[r];
        }
        // ---- init feat with h[src]*w[rel]: gathers overlap with MFMA below ----
        float feat[NT_O][4];
#pragma unroll
        for (int nt = 0; nt < NT_O; ++nt) {
            int o = nt * 16 + lrow;
#pragma unroll
            for (int r = 0; r < 4; ++r)
                feat[nt][r] = (o < OUT_FEAT) ? hp[r][o] * wp[r][o] : 0.f;
        }
        // ---- prefetch next tile ----
        int next = tile + gstride;
        bool more = next < ntiles;
        {
            int pidx = more ? next : cur;
            int slot = lo + pidx * 16;
            int pe = TOWS ? perm[slot + lrow] : (slot + lrow);
            const float* ap = efeat + (size_t)pe * IN_FEAT;
#pragma unroll
            for (int kt = 0; kt < 4; ++kt) {
                int k0 = kt * 32 + lk * 4, k1 = k0 + 16;
                pa[kt * 2]     = (k0 + 4 <= IN_FEAT) ? *reinterpret_cast<const float4*>(ap + k0)
                                                     : make_float4(0.f, 0.f, 0.f, 0.f);
                pa[kt * 2 + 1] = (k1 + 4 <= IN_FEAT) ? *reinterpret_cast<const float4*>(ap + k1)
                                                     : make_float4(0.f, 0.f, 0.f, 0.f);
            }
#pragma unroll
            for (int r = 0; r < 4; ++r) {
                int pr = TOWS ? perm[slot + lk * 4 + r] : (slot + lk * 4 + r);
                rl[r] = rel[pr]; sr[r] = src[pr]; dd[r] = dst[pr];
            }
        }

        // ---- 3 heads x 7 col-tiles x K=128, B from LDS ----
#pragma unroll 1
        for (int hh = 0; hh < NUM_HEADS; ++hh) {
            const char* Bh = Bc + hh * (NPH * KP * 2);
#pragma unroll
            for (int nt = 0; nt < NT_O; ++nt) {
                f32x4 acc = (f32x4){0.f, 0.f, 0.f, 0.f};
#pragma unroll
                for (int kt = 0; kt < 4; ++kt) {
                    short8 bfrag = *reinterpret_cast<const short8*>(
                        Bh + bkt[kt] + nt * 4096);
                    acc = __builtin_amdgcn_mfma_f32_16x16x32_bf16(afrag[kt], bfrag, acc, 0, 0, 0);
                }
                int o = nt * 16 + lrow;
                if (o < OUT_FEAT) {
                    int oo = hh * OUT_FEAT + o;
#pragma unroll
                    for (int r = 0; r < 4; ++r) {
                        float v = acc[r] * attn[aoff[r] + oo];
                        feat[nt][r] += (v > 0.f) ? v : 0.2f * v;
                    }
                }
            }
        }

        if (TOWS) {
            // per-wave transpose slice -> coalesced msg rows at perm slots
            unsigned short* sl = slice[wave];
#pragma unroll
            for (int nt = 0; nt < NT_O; ++nt) {
                int o = nt * 16 + lrow;
#pragma unroll
                for (int r = 0; r < 4; ++r)
                    sl[(lk * 4 + r) * NPH + o] = f2bf(feat[nt][r] * nm[r]);
            }
            asm volatile("s_waitcnt lgkmcnt(0)" ::: "memory");
            __builtin_amdgcn_sched_barrier(0);
            const int4* sp = reinterpret_cast<const int4*>(sl);
            int4* gp = reinterpret_cast<int4*>(msgws + (size_t)cur * (16 * NPH));
            gp[lane]       = sp[lane];
            gp[lane + 64]  = sp[lane + 64];
            gp[lane + 128] = sp[lane + 128];
            if (lane < 32) gp[lane + 192] = sp[lane + 192];
        } else {
#pragma unroll
            for (int nt = 0; nt < NT_O; ++nt) {
                int o = nt * 16 + lrow;
                if (o < OUT_FEAT) {
#pragma unroll
                    for (int r = 0; r < 4; ++r)
                        atomicAdd(&out[(size_t)ddc[r] * OUT_FEAT + o], feat[nt][r] * nm[r]);
                }
            }
        }

        if (!more) break;
        tile = next;
    }
}

// ---------------------------------------------------------------------------
// agg kernel: one wave per node; msg rows for node n are CONTIGUOUS
// (perm order == dst-sorted) -> pure streaming segmented sum, no atomics.
// norm already folded into msg. out += sum.
// ---------------------------------------------------------------------------
__global__ __launch_bounds__(256) void agg_kernel(
        const unsigned short* __restrict__ msgws, const int* __restrict__ offs,
        const int* __restrict__ cnt, float* __restrict__ out, int lo, int hi) {
    int wv = threadIdx.x >> 6, lane = threadIdx.x & 63;
    int n = blockIdx.x * 4 + wv;
    if (n >= N_NODES) return;
    int s0 = offs[n], deg = cnt[n];
    int start = s0 > lo ? s0 : lo;
    int end = (s0 + deg) < hi ? (s0 + deg) : hi;
    if (start >= end) return;
    if (lane >= OUT_FEAT / 2) return;
    const unsigned* mp = reinterpret_cast<const unsigned*>(msgws);
    float ax = 0.f, ay = 0.f;
    int k = start;
    for (; k + 2 <= end; k += 2) {
        unsigned u0 = mp[(size_t)(k - lo) * (NPH / 2) + lane];
        unsigned u1 = mp[(size_t)(k + 1 - lo) * (NPH / 2) + lane];
        ax += bf2f(u0 & 0xffffu) + bf2f(u1 & 0xffffu);
        ay += bf2f(u0 >> 16) + bf2f(u1 >> 16);
    }
    if (k < end) {
        unsigned u0 = mp[(size_t)(k - lo) * (NPH / 2) + lane];
        ax += bf2f(u0 & 0xffffu);
        ay += bf2f(u0 >> 16);
    }
    float2* op = reinterpret_cast<float2*>(out + (size_t)n * OUT_FEAT) + lane;
    float2 curv = *op;
    curv.x += ax; curv.y += ay;
    *op = curv;
}

extern "C" void kernel_launch(void* const* d_in, const int* in_sizes, int n_in,
                              void* d_out, int out_size, void* d_ws, size_t ws_size,
                              hipStream_t stream) {
    const float* h      = (const float*)d_in[0];
    const float* efeat  = (const float*)d_in[1];
    const float* norm   = (const float*)d_in[2];
    const float* weight = (const float*)d_in[3];
    const float* attn   = (const float*)d_in[4];
    const float* fc_w   = (const float*)d_in[5];
    const float* loop_w = (const float*)d_in[6];
    const int*   rel    = (const int*)d_in[7];
    const int*   src    = (const int*)d_in[8];
    const int*   dst    = (const int*)d_in[9];
    float* out = (float*)d_out;

    char* ws = (char*)d_ws;
    unsigned short* Bimg  = (unsigned short*)(ws + WS_B);
    unsigned short* LWimg = (unsigned short*)(ws + WS_LW);
    int* cnt    = (int*)(ws + WS_CNT);
    int* offs   = (int*)(ws + WS_OFFS);
    int* cursor = (int*)(ws + WS_CURSOR);
    int* bsum   = (int*)(ws + WS_BSUM);
    int* perm   = (int*)(ws + WS_PERM);
    unsigned short* msgws = (unsigned short*)(ws + WS_MSG);

    build_B<<<(NP * 16 + 255) / 256, 256, 0, stream>>>(fc_w, Bimg);
    build_LW<<<(NPH * 16 + 255) / 256, 256, 0, stream>>>(loop_w, LWimg);
    loop_gemm<<<(N_NODES + MB - 1) / MB, 512, 0, stream>>>(h, LWimg, out);

    long long avail = (long long)ws_size - (long long)WS_MSG;
    long long rows = (avail > 0) ? avail / (NPH * 2) : 0;
    rows = (rows / MB) * MB;
    if (rows > N_EDGES) rows = N_EDGES;

    if (rows >= 100000) {
        hipMemsetAsync(cnt, 0, NNODES_PAD * sizeof(int), stream);
        hist_kernel<<<(N_EDGES + 511) / 512, 512, 0, stream>>>(dst, cnt);
        scan1<<<NNODES_PAD / 1024, 1024, 0, stream>>>(cnt, offs, bsum);
        scan2<<<1, 64, 0, stream>>>(bsum);
        scan3<<<NNODES_PAD / 1024, 1024, 0, stream>>>(offs, bsum, cursor);
        scatter_kernel<<<(N_EDGES + 511) / 512, 512, 0, stream>>>(dst, cursor, perm);

        for (long long lo = 0; lo < N_EDGES; lo += rows) {
            long long hi = lo + rows; if (hi > N_EDGES) hi = N_EDGES;
            int ntiles = (int)((hi - lo) / 16);
            int nb = (ntiles + WPB - 1) / WPB; if (nb > 256) nb = 256;
            feat_kernel<true><<<nb, 768, 0, stream>>>(
                efeat, rel, Bimg, attn, h, weight, norm, src, dst, perm,
                out, msgws, (int)lo, ntiles);
            agg_kernel<<<(N_NODES + 3) / 4, 256, 0, stream>>>(
                msgws, offs, cnt, out, (int)lo, (int)hi);
        }
    } else {
        int ntiles = N_EDGES / 16;
        int nb = (ntiles + WPB - 1) / WPB; if (nb > 256) nb = 256;
        feat_kernel<false><<<nb, 768, 0, stream>>>(
            efeat, rel, Bimg, attn, h, weight, norm, src, dst, nullptr,
            out, msgws, 0, ntiles);
    }
}

// Round 8
// 440.193 us; speedup vs baseline: 1.7682x; 1.1214x over previous
//
#include <hip/hip_runtime.h>
#include <hip/hip_bf16.h>

#define N_NODES 50000
#define N_EDGES 800000
#define IN_FEAT 100
#define OUT_FEAT 100
#define NUM_RELS 200
#define NUM_HEADS 3

#define KP 128          // padded K (100 -> 128)
#define NPH 112         // per-head padded N (100 -> 112 = 7*16)
#define NP  336         // 3 * 112
#define MB  128         // node-rows per block (loop_gemm)
#define NT_O 7          // NPH/16
#define WPB 8           // waves per feat block (512 threads)
#define SLP 116         // slice row stride in ushorts (232 B -> conflict-free)
#define MSGW 100        // msg row width (ushorts) = 25 qwords

// ---- workspace layout (bytes) ----
#define WS_B       0u           // fc_w^T bf16 image, per-head swizzled: 86016
#define WS_LW      86016u       // loop_w^T bf16 image (linear): 28672
#define WS_CNT     114688u      // 50176 ints
#define WS_OFFS    315392u
#define WS_CURSOR  516096u
#define WS_BSUM    716800u      // 64 ints
#define WS_SLOT    717056u      // slotmap[e]: 800000 ints
#define WS_PERM    3917056u     // perm[p] = e: 800000 ints
#define WS_MSG     7117056u     // bf16 msg rows, 100 ushorts (200 B) each, slot order
#define WS_NEEDED  167117056u
#define NNODES_PAD 50176        // 49*1024

typedef __attribute__((ext_vector_type(8))) short short8;
typedef __attribute__((ext_vector_type(4))) float f32x4;

__device__ __forceinline__ unsigned short f2bf(float f) {
    unsigned u = __builtin_bit_cast(unsigned, f);
    unsigned r = u + 0x7FFFu + ((u >> 16) & 1u);
    return (unsigned short)(r >> 16);
}
__device__ __forceinline__ float bf2f(unsigned hs) {
    return __builtin_bit_cast(float, hs << 16);
}

// ---------------------------------------------------------------------------
// B = fc_w^T bf16, per-head regions, XOR-swizzled (proven layout):
// granule g of row (head,nl) at byte  head*28672 + nl*256 + ((g*16) ^ ((nl&7)<<4))
// granule elem j in [0,8): k = kt*32 + (j>>2)*16 + g4*4 + (j&3)
// ---------------------------------------------------------------------------
__global__ __launch_bounds__(256) void build_B(const float* __restrict__ fc_w,
                                               unsigned short* __restrict__ Bws) {
    int idx = blockIdx.x * 256 + threadIdx.x;     // granule id: n*16 + g
    if (idx >= NP * 16) return;
    int n = idx >> 4, g = idx & 15;
    int head = n / NPH, nl = n - head * NPH;
    int kt = g >> 2, g4 = g & 3;
    unsigned p[4];
#pragma unroll
    for (int half = 0; half < 2; ++half) {
#pragma unroll
        for (int jp = 0; jp < 2; ++jp) {
            int k_lo = kt * 32 + half * 16 + g4 * 4 + jp * 2;
            int k_hi = k_lo + 1;
            float vlo = (k_lo < IN_FEAT && nl < OUT_FEAT)
                      ? fc_w[k_lo * (OUT_FEAT * NUM_HEADS) + head * OUT_FEAT + nl] : 0.f;
            float vhi = (k_hi < IN_FEAT && nl < OUT_FEAT)
                      ? fc_w[k_hi * (OUT_FEAT * NUM_HEADS) + head * OUT_FEAT + nl] : 0.f;
            p[half * 2 + jp] = (unsigned)f2bf(vlo) | ((unsigned)f2bf(vhi) << 16);
        }
    }
    unsigned off = (unsigned)(head * (NPH * KP * 2)) +
                   (((unsigned)(nl * (KP * 2) + g * 16)) ^ (((unsigned)(nl & 7)) << 4));
    *reinterpret_cast<int4*>(reinterpret_cast<char*>(Bws) + off) =
        make_int4((int)p[0], (int)p[1], (int)p[2], (int)p[3]);
}

// loop_w^T bf16 image, LINEAR (read from L2 by loop_gemm fragments)
__global__ __launch_bounds__(256) void build_LW(const float* __restrict__ loop_w,
                                                unsigned short* __restrict__ LWws) {
    int idx = blockIdx.x * 256 + threadIdx.x;
    if (idx >= NPH * 16) return;
    int nl = idx >> 4, g = idx & 15;
    int kt = g >> 2, g4 = g & 3;
    unsigned p[4];
#pragma unroll
    for (int half = 0; half < 2; ++half) {
#pragma unroll
        for (int jp = 0; jp < 2; ++jp) {
            int k_lo = kt * 32 + half * 16 + g4 * 4 + jp * 2;
            int k_hi = k_lo + 1;
            float vlo = (k_lo < IN_FEAT && nl < OUT_FEAT) ? loop_w[k_lo * OUT_FEAT + nl] : 0.f;
            float vhi = (k_hi < IN_FEAT && nl < OUT_FEAT) ? loop_w[k_hi * OUT_FEAT + nl] : 0.f;
            p[half * 2 + jp] = (unsigned)f2bf(vlo) | ((unsigned)f2bf(vhi) << 16);
        }
    }
    reinterpret_cast<int4*>(LWws)[idx] = make_int4((int)p[0], (int)p[1], (int)p[2], (int)p[3]);
}

// ---------------------------------------------------------------------------
// Self-loop GEMM: out = h @ loop_w. Zero LDS/barriers; LW from L2.
// ---------------------------------------------------------------------------
__global__ __launch_bounds__(512, 2) void loop_gemm(const float* __restrict__ h,
                                                    const unsigned short* __restrict__ LWimg,
                                                    float* __restrict__ out) {
    const int tid = threadIdx.x;
    const int wave = tid >> 6, lane = tid & 63;
    const int lrow = lane & 15, lk = lane >> 4;
    const int rbase = blockIdx.x * MB;
    const int grow = rbase + wave * 16 + lrow;
    const bool ok = grow < N_NODES;
    const float* ap = h + (size_t)grow * IN_FEAT;

    short8 afrag[4];
#pragma unroll
    for (int kt = 0; kt < 4; ++kt) {
        int k0 = kt * 32 + lk * 4, k1 = k0 + 16;
        float4 va = (ok && k0 + 4 <= IN_FEAT) ? *reinterpret_cast<const float4*>(ap + k0)
                                              : make_float4(0.f, 0.f, 0.f, 0.f);
        float4 vb = (ok && k1 + 4 <= IN_FEAT) ? *reinterpret_cast<const float4*>(ap + k1)
                                              : make_float4(0.f, 0.f, 0.f, 0.f);
        afrag[kt][0] = (short)f2bf(va.x); afrag[kt][1] = (short)f2bf(va.y);
        afrag[kt][2] = (short)f2bf(va.z); afrag[kt][3] = (short)f2bf(va.w);
        afrag[kt][4] = (short)f2bf(vb.x); afrag[kt][5] = (short)f2bf(vb.y);
        afrag[kt][6] = (short)f2bf(vb.z); afrag[kt][7] = (short)f2bf(vb.w);
    }

#pragma unroll
    for (int nt = 0; nt < NT_O; ++nt) {
        f32x4 acc = (f32x4){0.f, 0.f, 0.f, 0.f};
#pragma unroll
        for (int kt = 0; kt < 4; ++kt) {
            short8 bfrag = *reinterpret_cast<const short8*>(
                LWimg + ((nt * 16 + lrow) * KP + kt * 32 + lk * 8));
            acc = __builtin_amdgcn_mfma_f32_16x16x32_bf16(afrag[kt], bfrag, acc, 0, 0, 0);
        }
        int o = nt * 16 + lrow;
        if (o < OUT_FEAT) {
#pragma unroll
            for (int r = 0; r < 4; ++r) {
                int crow = rbase + wave * 16 + lk * 4 + r;
                if (crow < N_NODES) out[(size_t)crow * OUT_FEAT + o] = acc[r];
            }
        }
    }
}

// ---------------------------------------------------------------------------
// CSR construction
// ---------------------------------------------------------------------------
__global__ __launch_bounds__(512) void hist_kernel(const int* __restrict__ dst,
                                                   int* __restrict__ cnt) {
    int e = blockIdx.x * 512 + threadIdx.x;
    if (e < N_EDGES) atomicAdd(&cnt[dst[e]], 1);
}

__global__ __launch_bounds__(1024) void scan1(const int* __restrict__ cnt,
                                              int* __restrict__ offs,
                                              int* __restrict__ bsum) {
    __shared__ int s[1024];
    int i = blockIdx.x * 1024 + threadIdx.x;
    int v = (i < N_NODES) ? cnt[i] : 0;
    s[threadIdx.x] = v;
    __syncthreads();
    for (int d = 1; d < 1024; d <<= 1) {
        int t = (threadIdx.x >= d) ? s[threadIdx.x - d] : 0;
        __syncthreads();
        s[threadIdx.x] += t;
        __syncthreads();
    }
    offs[i] = s[threadIdx.x] - v;
    if (threadIdx.x == 1023) bsum[blockIdx.x] = s[1023];
}

__global__ __launch_bounds__(64) void scan2(int* __restrict__ bsum) {
    __shared__ int s[64];
    int v = (threadIdx.x < NNODES_PAD / 1024) ? bsum[threadIdx.x] : 0;
    s[threadIdx.x] = v;
    __syncthreads();
    for (int d = 1; d < 64; d <<= 1) {
        int t = (threadIdx.x >= d) ? s[threadIdx.x - d] : 0;
        __syncthreads();
        s[threadIdx.x] += t;
        __syncthreads();
    }
    bsum[threadIdx.x] = s[threadIdx.x] - v;
}

__global__ __launch_bounds__(1024) void scan3(int* __restrict__ offs,
                                              const int* __restrict__ bsum,
                                              int* __restrict__ cursor) {
    int i = blockIdx.x * 1024 + threadIdx.x;
    int v = offs[i] + bsum[blockIdx.x];
    offs[i] = v;
    cursor[i] = v;
}

// perm[p]=e (gather map for agg) and slotmap[e]=p (scatter map for feat)
__global__ __launch_bounds__(512) void scatter_kernel(const int* __restrict__ dst,
                                                      int* __restrict__ cursor,
                                                      int* __restrict__ perm,
                                                      int* __restrict__ slotmap) {
    int e = blockIdx.x * 512 + threadIdx.x;
    if (e < N_EDGES) {
        int p = atomicAdd(&cursor[dst[e]], 1);
        perm[p] = e;
        slotmap[e] = p;
    }
}

// ---------------------------------------------------------------------------
// feat kernel v8: NATURAL edge order (coalesced efeat/rel; sequential stream),
// persistent full-B LDS (one barrier), 8 waves grid-stride, A+rel prefetched
// one tile ahead; attention-feat ONLY (h*w and norm live in agg); bf16 rows
// scattered to dst-sorted slots via slotmap (stores are latency-free).
// (512,2): proven no-spill register allocation (rounds 1/3/4).
// ---------------------------------------------------------------------------
template<bool TOWS>
__global__ __launch_bounds__(512, 2) void feat_kernel(
        const float* __restrict__ efeat, const int* __restrict__ rel,
        const unsigned short* __restrict__ Bimg, const float* __restrict__ attn,
        const float* __restrict__ h, const float* __restrict__ weight,
        const float* __restrict__ norm, const int* __restrict__ src,
        const int* __restrict__ dst, const int* __restrict__ slotmap,
        float* __restrict__ out, unsigned short* __restrict__ msgws,
        int ntiles) {

    __shared__ __align__(16) unsigned short Blds[NP * KP];        // 86016 B
    __shared__ __align__(16) unsigned short slice[WPB][16 * SLP]; // 29696 B

    const int tid = threadIdx.x;
    {
        const int4* sp = reinterpret_cast<const int4*>(Bimg);
        int4* dp = reinterpret_cast<int4*>(Blds);
        for (int i = tid; i < NP * KP / 8; i += 512) dp[i] = sp[i];
    }
    __syncthreads();   // the only barrier

    const int wave = tid >> 6, lane = tid & 63;
    const int lrow = lane & 15, lk = lane >> 4;
    const int gstride = gridDim.x * WPB;
    int tile = blockIdx.x * WPB + wave;
    if (tile >= ntiles) return;

    const char* Bc = reinterpret_cast<const char*>(Blds);
    int bkt[4];
#pragma unroll
    for (int kt = 0; kt < 4; ++kt)
        bkt[kt] = lrow * (KP * 2) + ((kt * 64 + lk * 16) ^ ((lrow & 7) << 4));

    // ---- prefetch A + rel for first tile (natural order: coalesced) ----
    float4 pa[8];
    int prl[4];
    {
        const float* ap = efeat + (size_t)(tile * 16 + lrow) * IN_FEAT;
#pragma unroll
        for (int kt = 0; kt < 4; ++kt) {
            int k0 = kt * 32 + lk * 4, k1 = k0 + 16;
            pa[kt * 2]     = (k0 + 4 <= IN_FEAT) ? *reinterpret_cast<const float4*>(ap + k0)
                                                 : make_float4(0.f, 0.f, 0.f, 0.f);
            pa[kt * 2 + 1] = (k1 + 4 <= IN_FEAT) ? *reinterpret_cast<const float4*>(ap + k1)
                                                 : make_float4(0.f, 0.f, 0.f, 0.f);
        }
        const int* rp = rel + tile * 16 + lk * 4;
#pragma unroll
        for (int r = 0; r < 4; ++r) prl[r] = rp[r];
    }

    while (true) {
        const int cur = tile;
        const int tb = cur * 16;
        // ---- consume prefetched A ----
        short8 afrag[4];
#pragma unroll
        for (int kt = 0; kt < 4; ++kt) {
            float4 va = pa[kt * 2], vb = pa[kt * 2 + 1];
            afrag[kt][0] = (short)f2bf(va.x); afrag[kt][1] = (short)f2bf(va.y);
            afrag[kt][2] = (short)f2bf(va.z); afrag[kt][3] = (short)f2bf(va.w);
            afrag[kt][4] = (short)f2bf(vb.x); afrag[kt][5] = (short)f2bf(vb.y);
            afrag[kt][6] = (short)f2bf(vb.z); afrag[kt][7] = (short)f2bf(vb.w);
        }
        int aoff[4];
#pragma unroll
        for (int r = 0; r < 4; ++r) aoff[r] = prl[r] * (NUM_HEADS * OUT_FEAT);

        // ---- prefetch next tile ----
        int next = tile + gstride;
        bool more = next < ntiles;
        {
            int pidx = more ? next : cur;
            const float* ap = efeat + (size_t)(pidx * 16 + lrow) * IN_FEAT;
#pragma unroll
            for (int kt = 0; kt < 4; ++kt) {
                int k0 = kt * 32 + lk * 4, k1 = k0 + 16;
                pa[kt * 2]     = (k0 + 4 <= IN_FEAT) ? *reinterpret_cast<const float4*>(ap + k0)
                                                     : make_float4(0.f, 0.f, 0.f, 0.f);
                pa[kt * 2 + 1] = (k1 + 4 <= IN_FEAT) ? *reinterpret_cast<const float4*>(ap + k1)
                                                     : make_float4(0.f, 0.f, 0.f, 0.f);
            }
            const int* rp = rel + pidx * 16 + lk * 4;
#pragma unroll
            for (int r = 0; r < 4; ++r) prl[r] = rp[r];
        }

        // ---- 3 heads x 7 col-tiles x K=128, B from LDS ----
        float feat[NT_O][4];
#pragma unroll
        for (int nt = 0; nt < NT_O; ++nt)
#pragma unroll
            for (int r = 0; r < 4; ++r) feat[nt][r] = 0.f;

#pragma unroll 1
        for (int hh = 0; hh < NUM_HEADS; ++hh) {
            const char* Bh = Bc + hh * (NPH * KP * 2);
#pragma unroll
            for (int nt = 0; nt < NT_O; ++nt) {
                f32x4 acc = (f32x4){0.f, 0.f, 0.f, 0.f};
#pragma unroll
                for (int kt = 0; kt < 4; ++kt) {
                    short8 bfrag = *reinterpret_cast<const short8*>(
                        Bh + bkt[kt] + nt * 4096);
                    acc = __builtin_amdgcn_mfma_f32_16x16x32_bf16(afrag[kt], bfrag, acc, 0, 0, 0);
                }
                int o = nt * 16 + lrow;
                if (o < OUT_FEAT) {
                    int oo = hh * OUT_FEAT + o;
#pragma unroll
                    for (int r = 0; r < 4; ++r) {
                        float v = acc[r] * attn[aoff[r] + oo];
                        feat[nt][r] += (v > 0.f) ? v : 0.2f * v;
                    }
                }
            }
        }

        if (TOWS) {
            // per-wave transpose slice (stride 116 -> 32-bank spread, free)
            unsigned short* sl = slice[wave];
#pragma unroll
            for (int nt = 0; nt < NT_O; ++nt) {
                int o = nt * 16 + lrow;
                if (o < OUT_FEAT) {
#pragma unroll
                    for (int r = 0; r < 4; ++r)
                        sl[(lk * 4 + r) * SLP + o] = f2bf(feat[nt][r]);
                }
            }
            asm volatile("s_waitcnt lgkmcnt(0)" ::: "memory");
            __builtin_amdgcn_sched_barrier(0);
            // scatter rows to dst-sorted slots: 25 qwords (200 B) per edge
            const int row = lane >> 2, part = lane & 3;
            const int slot = slotmap[tb + row];
            const unsigned long long* sq =
                reinterpret_cast<const unsigned long long*>(slice[wave]);
            unsigned long long* mq = reinterpret_cast<unsigned long long*>(msgws);
#pragma unroll
            for (int j = 0; j < 7; ++j) {
                int idx = part + 4 * j;
                if (idx < 25)
                    mq[(size_t)slot * 25 + idx] = sq[row * (SLP / 4) + idx];
            }
        } else {
            // fallback: fully fused atomic epilogue (h*w + feat)*norm
            int sr_r[4], d_r[4]; float nm_r[4]; int rl_r[4];
#pragma unroll
            for (int r = 0; r < 4; ++r) {
                int ei = tb + lk * 4 + r;
                sr_r[r] = src[ei]; d_r[r] = dst[ei]; nm_r[r] = norm[d_r[r]];
                rl_r[r] = aoff[r] / (NUM_HEADS * OUT_FEAT);
            }
#pragma unroll
            for (int nt = 0; nt < NT_O; ++nt) {
                int o = nt * 16 + lrow;
                if (o < OUT_FEAT) {
#pragma unroll
                    for (int r = 0; r < 4; ++r) {
                        float mg = h[(size_t)sr_r[r] * IN_FEAT + o] *
                                   weight[(size_t)rl_r[r] * OUT_FEAT + o];
                        atomicAdd(&out[(size_t)d_r[r] * OUT_FEAT + o],
                                  (mg + feat[nt][r]) * nm_r[r]);
                    }
                }
            }
        }

        if (!more) break;
        tile = next;
    }
}

// ---------------------------------------------------------------------------
// agg kernel: one wave per node; msg rows CONTIGUOUS in slot order (stream);
// per edge adds h[src]*w[rel] in f32 (src/rel via perm broadcast; h L3-hot);
// out += sum * norm[n]. No atomics, no LDS -> max TLP.
// ---------------------------------------------------------------------------
__global__ __launch_bounds__(256, 2) void agg_kernel(
        const unsigned short* __restrict__ msgws, const int* __restrict__ offs,
        const int* __restrict__ cnt, const int* __restrict__ perm,
        const int* __restrict__ src, const int* __restrict__ rel,
        const float* __restrict__ h, const float* __restrict__ weight,
        const float* __restrict__ norm, float* __restrict__ out) {
    int wv = threadIdx.x >> 6, lane = threadIdx.x & 63;
    int n = blockIdx.x * 4 + wv;
    if (n >= N_NODES) return;
    int start = offs[n], deg = cnt[n];
    if (deg == 0 || lane >= OUT_FEAT / 2) return;
    const unsigned* mp = reinterpret_cast<const unsigned*>(msgws);
    float ax = 0.f, ay = 0.f;
    int k = start, end = start + deg;
    for (; k + 2 <= end; k += 2) {
        int e0 = perm[k], e1 = perm[k + 1];
        int s0 = src[e0], s1 = src[e1];
        int r0 = rel[e0], r1 = rel[e1];
        unsigned u0 = mp[(size_t)k * (MSGW / 2) + lane];
        unsigned u1 = mp[(size_t)(k + 1) * (MSGW / 2) + lane];
        float2 h0 = *reinterpret_cast<const float2*>(h + (size_t)s0 * IN_FEAT + 2 * lane);
        float2 w0 = *reinterpret_cast<const float2*>(weight + (size_t)r0 * OUT_FEAT + 2 * lane);
        float2 h1 = *reinterpret_cast<const float2*>(h + (size_t)s1 * IN_FEAT + 2 * lane);
        float2 w1 = *reinterpret_cast<const float2*>(weight + (size_t)r1 * OUT_FEAT + 2 * lane);
        ax += h0.x * w0.x + bf2f(u0 & 0xffffu) + h1.x * w1.x + bf2f(u1 & 0xffffu);
        ay += h0.y * w0.y + bf2f(u0 >> 16) + h1.y * w1.y + bf2f(u1 >> 16);
    }
    if (k < end) {
        int e0 = perm[k];
        int s0 = src[e0], r0 = rel[e0];
        unsigned u0 = mp[(size_t)k * (MSGW / 2) + lane];
        float2 h0 = *reinterpret_cast<const float2*>(h + (size_t)s0 * IN_FEAT + 2 * lane);
        float2 w0 = *reinterpret_cast<const float2*>(weight + (size_t)r0 * OUT_FEAT + 2 * lane);
        ax += h0.x * w0.x + bf2f(u0 & 0xffffu);
        ay += h0.y * w0.y + bf2f(u0 >> 16);
    }
    float nm = norm[n];
    float2* op = reinterpret_cast<float2*>(out + (size_t)n * OUT_FEAT) + lane;
    float2 curv = *op;
    curv.x += ax * nm; curv.y += ay * nm;
    *op = curv;
}

extern "C" void kernel_launch(void* const* d_in, const int* in_sizes, int n_in,
                              void* d_out, int out_size, void* d_ws, size_t ws_size,
                              hipStream_t stream) {
    const float* h      = (const float*)d_in[0];
    const float* efeat  = (const float*)d_in[1];
    const float* norm   = (const float*)d_in[2];
    const float* weight = (const float*)d_in[3];
    const float* attn   = (const float*)d_in[4];
    const float* fc_w   = (const float*)d_in[5];
    const float* loop_w = (const float*)d_in[6];
    const int*   rel    = (const int*)d_in[7];
    const int*   src    = (const int*)d_in[8];
    const int*   dst    = (const int*)d_in[9];
    float* out = (float*)d_out;

    char* ws = (char*)d_ws;
    unsigned short* Bimg  = (unsigned short*)(ws + WS_B);
    unsigned short* LWimg = (unsigned short*)(ws + WS_LW);
    int* cnt     = (int*)(ws + WS_CNT);
    int* offs    = (int*)(ws + WS_OFFS);
    int* cursor  = (int*)(ws + WS_CURSOR);
    int* bsum    = (int*)(ws + WS_BSUM);
    int* slotmap = (int*)(ws + WS_SLOT);
    int* perm    = (int*)(ws + WS_PERM);
    unsigned short* msgws = (unsigned short*)(ws + WS_MSG);

    build_B<<<(NP * 16 + 255) / 256, 256, 0, stream>>>(fc_w, Bimg);
    build_LW<<<(NPH * 16 + 255) / 256, 256, 0, stream>>>(loop_w, LWimg);
    loop_gemm<<<(N_NODES + MB - 1) / MB, 512, 0, stream>>>(h, LWimg, out);

    const int ntiles = N_EDGES / 16;

    if (ws_size >= (size_t)WS_NEEDED) {
        hipMemsetAsync(cnt, 0, NNODES_PAD * sizeof(int), stream);
        hist_kernel<<<(N_EDGES + 511) / 512, 512, 0, stream>>>(dst, cnt);
        scan1<<<NNODES_PAD / 1024, 1024, 0, stream>>>(cnt, offs, bsum);
        scan2<<<1, 64, 0, stream>>>(bsum);
        scan3<<<NNODES_PAD / 1024, 1024, 0, stream>>>(offs, bsum, cursor);
        scatter_kernel<<<(N_EDGES + 511) / 512, 512, 0, stream>>>(dst, cursor, perm, slotmap);

        feat_kernel<true><<<256, 512, 0, stream>>>(
            efeat, rel, Bimg, attn, h, weight, norm, src, dst, slotmap,
            out, msgws, ntiles);
        agg_kernel<<<(N_NODES + 3) / 4, 256, 0, stream>>>(
            msgws, offs, cnt, perm, src, rel, h, weight, norm, out);
    } else {
        feat_kernel<false><<<256, 512, 0, stream>>>(
            efeat, rel, Bimg, attn, h, weight, norm, src, dst, nullptr,
            out, msgws, ntiles);
    }
}

// Round 9
// 407.391 us; speedup vs baseline: 1.9106x; 1.0805x over previous
//
#include <hip/hip_runtime.h>
#include <hip/hip_bf16.h>

#define N_NODES 50000
#define N_EDGES 800000
#define IN_FEAT 100
#define OUT_FEAT 100
#define NUM_RELS 200
#define NUM_HEADS 3

#define KP 128          // padded K (100 -> 128)
#define NPH 112         // per-head padded N for MFMA tiling (7*16)
#define MB  128         // node-rows per block (loop_gemm)
#define NT_O 7          // NPH/16
#define WPB 8           // waves per feat block (512 threads)
#define MSGW 100        // msg row width (ushorts) = 200 B
#define BROWS 312       // compact B rows: 3*100 + 12 guard
#define HSTRIDE 25600   // bytes per head in compact B (100 rows * 256 B)

// ---- workspace layout (bytes) ----
#define WS_B       0u           // compact fc_w^T bf16 image: 79872
#define WS_LW      86016u       // loop_w^T bf16 image (linear): 28672
#define WS_CNT     114688u      // 50176 ints
#define WS_OFFS    315392u
#define WS_CURSOR  516096u
#define WS_BSUM    716800u      // 64 ints
#define WS_SLOT    717056u      // slotmap[e]: 800000 ints
#define WS_META    3917056u     // meta[p] = src | (rel<<16): 800000 ints
#define WS_MSG     7117056u     // bf16 msg rows, 100 ushorts (200 B) each, slot order
#define WS_NEEDED  167117056u
#define NNODES_PAD 50176        // 49*1024

typedef __attribute__((ext_vector_type(8))) short short8;
typedef __attribute__((ext_vector_type(4))) float f32x4;

__device__ __forceinline__ unsigned short f2bf(float f) {
    unsigned u = __builtin_bit_cast(unsigned, f);
    unsigned r = u + 0x7FFFu + ((u >> 16) & 1u);
    return (unsigned short)(r >> 16);
}
__device__ __forceinline__ float bf2f(unsigned hs) {
    return __builtin_bit_cast(float, hs << 16);
}

// ---------------------------------------------------------------------------
// Compact B = fc_w^T bf16: 312 rows of 256 B. Row n (= head*100 + nl for
// n<300; zero guard rows for n>=300) holds fc column (head, nl), XOR-swizzled:
// granule g at byte n*256 + ((g*16) ^ ((nl&7)<<4)); elem j in [0,8):
// k = kt*32 + (j>>2)*16 + g4*4 + (j&3). Reads for padded rows nl>=100 land in
// the next head's rows / guard -> garbage feeds only discarded columns.
// ---------------------------------------------------------------------------
__global__ __launch_bounds__(256) void build_B(const float* __restrict__ fc_w,
                                               unsigned short* __restrict__ Bws) {
    int idx = blockIdx.x * 256 + threadIdx.x;     // granule id: n*16 + g
    if (idx >= BROWS * 16) return;
    int n = idx >> 4, g = idx & 15;
    int head = n / 100, nl = n - head * 100;      // head==3 -> guard rows
    int kt = g >> 2, g4 = g & 3;
    unsigned p[4] = {0u, 0u, 0u, 0u};
    if (n < 300) {
#pragma unroll
        for (int half = 0; half < 2; ++half) {
#pragma unroll
            for (int jp = 0; jp < 2; ++jp) {
                int k_lo = kt * 32 + half * 16 + g4 * 4 + jp * 2;
                int k_hi = k_lo + 1;
                float vlo = (k_lo < IN_FEAT)
                          ? fc_w[k_lo * (OUT_FEAT * NUM_HEADS) + head * OUT_FEAT + nl] : 0.f;
                float vhi = (k_hi < IN_FEAT)
                          ? fc_w[k_hi * (OUT_FEAT * NUM_HEADS) + head * OUT_FEAT + nl] : 0.f;
                p[half * 2 + jp] = (unsigned)f2bf(vlo) | ((unsigned)f2bf(vhi) << 16);
            }
        }
    }
    unsigned off = (unsigned)(n * 256) + (((unsigned)(g * 16)) ^ (((unsigned)(nl & 7)) << 4));
    *reinterpret_cast<int4*>(reinterpret_cast<char*>(Bws) + off) =
        make_int4((int)p[0], (int)p[1], (int)p[2], (int)p[3]);
}

// loop_w^T bf16 image, LINEAR (read from L2 by loop_gemm fragments)
__global__ __launch_bounds__(256) void build_LW(const float* __restrict__ loop_w,
                                                unsigned short* __restrict__ LWws) {
    int idx = blockIdx.x * 256 + threadIdx.x;
    if (idx >= NPH * 16) return;
    int nl = idx >> 4, g = idx & 15;
    int kt = g >> 2, g4 = g & 3;
    unsigned p[4];
#pragma unroll
    for (int half = 0; half < 2; ++half) {
#pragma unroll
        for (int jp = 0; jp < 2; ++jp) {
            int k_lo = kt * 32 + half * 16 + g4 * 4 + jp * 2;
            int k_hi = k_lo + 1;
            float vlo = (k_lo < IN_FEAT && nl < OUT_FEAT) ? loop_w[k_lo * OUT_FEAT + nl] : 0.f;
            float vhi = (k_hi < IN_FEAT && nl < OUT_FEAT) ? loop_w[k_hi * OUT_FEAT + nl] : 0.f;
            p[half * 2 + jp] = (unsigned)f2bf(vlo) | ((unsigned)f2bf(vhi) << 16);
        }
    }
    reinterpret_cast<int4*>(LWws)[idx] = make_int4((int)p[0], (int)p[1], (int)p[2], (int)p[3]);
}

// ---------------------------------------------------------------------------
// Self-loop GEMM: out = h @ loop_w. Zero LDS/barriers; LW from L2.
// ---------------------------------------------------------------------------
__global__ __launch_bounds__(512, 2) void loop_gemm(const float* __restrict__ h,
                                                    const unsigned short* __restrict__ LWimg,
                                                    float* __restrict__ out) {
    const int tid = threadIdx.x;
    const int wave = tid >> 6, lane = tid & 63;
    const int lrow = lane & 15, lk = lane >> 4;
    const int rbase = blockIdx.x * MB;
    const int grow = rbase + wave * 16 + lrow;
    const bool ok = grow < N_NODES;
    const float* ap = h + (size_t)grow * IN_FEAT;

    short8 afrag[4];
#pragma unroll
    for (int kt = 0; kt < 4; ++kt) {
        int k0 = kt * 32 + lk * 4, k1 = k0 + 16;
        float4 va = (ok && k0 + 4 <= IN_FEAT) ? *reinterpret_cast<const float4*>(ap + k0)
                                              : make_float4(0.f, 0.f, 0.f, 0.f);
        float4 vb = (ok && k1 + 4 <= IN_FEAT) ? *reinterpret_cast<const float4*>(ap + k1)
                                              : make_float4(0.f, 0.f, 0.f, 0.f);
        afrag[kt][0] = (short)f2bf(va.x); afrag[kt][1] = (short)f2bf(va.y);
        afrag[kt][2] = (short)f2bf(va.z); afrag[kt][3] = (short)f2bf(va.w);
        afrag[kt][4] = (short)f2bf(vb.x); afrag[kt][5] = (short)f2bf(vb.y);
        afrag[kt][6] = (short)f2bf(vb.z); afrag[kt][7] = (short)f2bf(vb.w);
    }

#pragma unroll
    for (int nt = 0; nt < NT_O; ++nt) {
        f32x4 acc = (f32x4){0.f, 0.f, 0.f, 0.f};
#pragma unroll
        for (int kt = 0; kt < 4; ++kt) {
            short8 bfrag = *reinterpret_cast<const short8*>(
                LWimg + ((nt * 16 + lrow) * KP + kt * 32 + lk * 8));
            acc = __builtin_amdgcn_mfma_f32_16x16x32_bf16(afrag[kt], bfrag, acc, 0, 0, 0);
        }
        int o = nt * 16 + lrow;
        if (o < OUT_FEAT) {
#pragma unroll
            for (int r = 0; r < 4; ++r) {
                int crow = rbase + wave * 16 + lk * 4 + r;
                if (crow < N_NODES) out[(size_t)crow * OUT_FEAT + o] = acc[r];
            }
        }
    }
}

// ---------------------------------------------------------------------------
// CSR construction
// ---------------------------------------------------------------------------
__global__ __launch_bounds__(512) void hist_kernel(const int* __restrict__ dst,
                                                   int* __restrict__ cnt) {
    int e = blockIdx.x * 512 + threadIdx.x;
    if (e < N_EDGES) atomicAdd(&cnt[dst[e]], 1);
}

__global__ __launch_bounds__(1024) void scan1(const int* __restrict__ cnt,
                                              int* __restrict__ offs,
                                              int* __restrict__ bsum) {
    __shared__ int s[1024];
    int i = blockIdx.x * 1024 + threadIdx.x;
    int v = (i < N_NODES) ? cnt[i] : 0;
    s[threadIdx.x] = v;
    __syncthreads();
    for (int d = 1; d < 1024; d <<= 1) {
        int t = (threadIdx.x >= d) ? s[threadIdx.x - d] : 0;
        __syncthreads();
        s[threadIdx.x] += t;
        __syncthreads();
    }
    offs[i] = s[threadIdx.x] - v;
    if (threadIdx.x == 1023) bsum[blockIdx.x] = s[1023];
}

__global__ __launch_bounds__(64) void scan2(int* __restrict__ bsum) {
    __shared__ int s[64];
    int v = (threadIdx.x < NNODES_PAD / 1024) ? bsum[threadIdx.x] : 0;
    s[threadIdx.x] = v;
    __syncthreads();
    for (int d = 1; d < 64; d <<= 1) {
        int t = (threadIdx.x >= d) ? s[threadIdx.x - d] : 0;
        __syncthreads();
        s[threadIdx.x] += t;
        __syncthreads();
    }
    bsum[threadIdx.x] = s[threadIdx.x] - v;
}

__global__ __launch_bounds__(1024) void scan3(int* __restrict__ offs,
                                              const int* __restrict__ bsum,
                                              int* __restrict__ cursor) {
    int i = blockIdx.x * 1024 + threadIdx.x;
    int v = offs[i] + bsum[blockIdx.x];
    offs[i] = v;
    cursor[i] = v;
}

// slotmap[e]=p (scatter map for feat) and meta[p]=src|rel<<16 (streams for agg)
__global__ __launch_bounds__(512) void scatter_kernel(const int* __restrict__ dst,
                                                      const int* __restrict__ src,
                                                      const int* __restrict__ rel,
                                                      int* __restrict__ cursor,
                                                      int* __restrict__ slotmap,
                                                      int* __restrict__ meta) {
    int e = blockIdx.x * 512 + threadIdx.x;
    if (e < N_EDGES) {
        int p = atomicAdd(&cursor[dst[e]], 1);
        slotmap[e] = p;
        meta[p] = (src[e] & 0xFFFF) | (rel[e] << 16);
    }
}

// ---------------------------------------------------------------------------
// feat kernel v9: NATURAL edge order, persistent compact-B LDS (79872 B ->
// 2 blocks/CU, 16 waves/CU), 8 waves grid-stride, A+rel prefetched one tile
// ahead; bf16 feat rows scattered directly to dst-sorted slots (no LDS slice).
// ---------------------------------------------------------------------------
template<bool TOWS>
__global__ __launch_bounds__(512, 2) void feat_kernel(
        const float* __restrict__ efeat, const int* __restrict__ rel,
        const unsigned short* __restrict__ Bimg, const float* __restrict__ attn,
        const float* __restrict__ h, const float* __restrict__ weight,
        const float* __restrict__ norm, const int* __restrict__ src,
        const int* __restrict__ dst, const int* __restrict__ slotmap,
        float* __restrict__ out, unsigned short* __restrict__ msgws,
        int ntiles) {

    __shared__ __align__(16) unsigned short Blds[BROWS * 128];   // 79872 B

    const int tid = threadIdx.x;
    {
        const int4* sp = reinterpret_cast<const int4*>(Bimg);
        int4* dp = reinterpret_cast<int4*>(Blds);
        for (int i = tid; i < BROWS * 128 / 8; i += 512) dp[i] = sp[i];
    }
    __syncthreads();   // the only barrier

    const int wave = tid >> 6, lane = tid & 63;
    const int lrow = lane & 15, lk = lane >> 4;
    const int gstride = gridDim.x * WPB;
    int tile = blockIdx.x * WPB + wave;
    if (tile >= ntiles) return;

    const char* Bc = reinterpret_cast<const char*>(Blds);
    int bkt[4];
#pragma unroll
    for (int kt = 0; kt < 4; ++kt)
        bkt[kt] = lrow * 256 + ((kt * 64 + lk * 16) ^ ((lrow & 7) << 4));

    // ---- prefetch A + rel for first tile (natural order: coalesced) ----
    float4 pa[8];
    int prl[4];
    {
        const float* ap = efeat + (size_t)(tile * 16 + lrow) * IN_FEAT;
#pragma unroll
        for (int kt = 0; kt < 4; ++kt) {
            int k0 = kt * 32 + lk * 4, k1 = k0 + 16;
            pa[kt * 2]     = (k0 + 4 <= IN_FEAT) ? *reinterpret_cast<const float4*>(ap + k0)
                                                 : make_float4(0.f, 0.f, 0.f, 0.f);
            pa[kt * 2 + 1] = (k1 + 4 <= IN_FEAT) ? *reinterpret_cast<const float4*>(ap + k1)
                                                 : make_float4(0.f, 0.f, 0.f, 0.f);
        }
        const int* rp = rel + tile * 16 + lk * 4;
#pragma unroll
        for (int r = 0; r < 4; ++r) prl[r] = rp[r];
    }

    while (true) {
        const int cur = tile;
        const int tb = cur * 16;
        // ---- consume prefetched A ----
        short8 afrag[4];
#pragma unroll
        for (int kt = 0; kt < 4; ++kt) {
            float4 va = pa[kt * 2], vb = pa[kt * 2 + 1];
            afrag[kt][0] = (short)f2bf(va.x); afrag[kt][1] = (short)f2bf(va.y);
            afrag[kt][2] = (short)f2bf(va.z); afrag[kt][3] = (short)f2bf(va.w);
            afrag[kt][4] = (short)f2bf(vb.x); afrag[kt][5] = (short)f2bf(vb.y);
            afrag[kt][6] = (short)f2bf(vb.z); afrag[kt][7] = (short)f2bf(vb.w);
        }
        int aoff[4];
#pragma unroll
        for (int r = 0; r < 4; ++r) aoff[r] = prl[r] * (NUM_HEADS * OUT_FEAT);

        // slot ids (TOWS) for this tile's 4 C-rows
        int slot_r[4];
        if (TOWS) {
#pragma unroll
            for (int r = 0; r < 4; ++r) slot_r[r] = slotmap[tb + lk * 4 + r];
        }

        // ---- prefetch next tile ----
        int next = tile + gstride;
        bool more = next < ntiles;
        {
            int pidx = more ? next : cur;
            const float* ap = efeat + (size_t)(pidx * 16 + lrow) * IN_FEAT;
#pragma unroll
            for (int kt = 0; kt < 4; ++kt) {
                int k0 = kt * 32 + lk * 4, k1 = k0 + 16;
                pa[kt * 2]     = (k0 + 4 <= IN_FEAT) ? *reinterpret_cast<const float4*>(ap + k0)
                                                     : make_float4(0.f, 0.f, 0.f, 0.f);
                pa[kt * 2 + 1] = (k1 + 4 <= IN_FEAT) ? *reinterpret_cast<const float4*>(ap + k1)
                                                     : make_float4(0.f, 0.f, 0.f, 0.f);
            }
            const int* rp = rel + pidx * 16 + lk * 4;
#pragma unroll
            for (int r = 0; r < 4; ++r) prl[r] = rp[r];
        }

        // ---- 3 heads x 7 col-tiles x K=128, B from LDS ----
        float feat[NT_O][4];
#pragma unroll
        for (int nt = 0; nt < NT_O; ++nt)
#pragma unroll
            for (int r = 0; r < 4; ++r) feat[nt][r] = 0.f;

#pragma unroll 1
        for (int hh = 0; hh < NUM_HEADS; ++hh) {
            const char* Bh = Bc + hh * HSTRIDE;
#pragma unroll
            for (int nt = 0; nt < NT_O; ++nt) {
                f32x4 acc = (f32x4){0.f, 0.f, 0.f, 0.f};
#pragma unroll
                for (int kt = 0; kt < 4; ++kt) {
                    short8 bfrag = *reinterpret_cast<const short8*>(
                        Bh + bkt[kt] + nt * 4096);
                    acc = __builtin_amdgcn_mfma_f32_16x16x32_bf16(afrag[kt], bfrag, acc, 0, 0, 0);
                }
                int o = nt * 16 + lrow;
                if (o < OUT_FEAT) {
                    int oo = hh * OUT_FEAT + o;
#pragma unroll
                    for (int r = 0; r < 4; ++r) {
                        float v = acc[r] * attn[aoff[r] + oo];
                        feat[nt][r] += (v > 0.f) ? v : 0.2f * v;
                    }
                }
            }
        }

        if (TOWS) {
            // direct scatter: per (nt,r) one store covers 4 slots x 16 ushorts
#pragma unroll
            for (int nt = 0; nt < NT_O; ++nt) {
                int o = nt * 16 + lrow;
                if (o < OUT_FEAT) {
#pragma unroll
                    for (int r = 0; r < 4; ++r)
                        msgws[(size_t)slot_r[r] * MSGW + o] = f2bf(feat[nt][r]);
                }
            }
        } else {
            // fallback: fully fused atomic epilogue (h*w + feat)*norm
            int sr_r[4], d_r[4]; float nm_r[4]; int rl_r[4];
#pragma unroll
            for (int r = 0; r < 4; ++r) {
                int ei = tb + lk * 4 + r;
                sr_r[r] = src[ei]; d_r[r] = dst[ei]; nm_r[r] = norm[d_r[r]];
                rl_r[r] = aoff[r] / (NUM_HEADS * OUT_FEAT);
            }
#pragma unroll
            for (int nt = 0; nt < NT_O; ++nt) {
                int o = nt * 16 + lrow;
                if (o < OUT_FEAT) {
#pragma unroll
                    for (int r = 0; r < 4; ++r) {
                        float mg = h[(size_t)sr_r[r] * IN_FEAT + o] *
                                   weight[(size_t)rl_r[r] * OUT_FEAT + o];
                        atomicAdd(&out[(size_t)d_r[r] * OUT_FEAT + o],
                                  (mg + feat[nt][r]) * nm_r[r]);
                    }
                }
            }
        }

        if (!more) break;
        tile = next;
    }
}

// ---------------------------------------------------------------------------
// agg kernel: one wave per node; msg + meta are contiguous streams in slot
// order; h/weight row-coalesced (h 20 MB L3-hot, weight 80 KB L2-hot);
// out += (sum) * norm[n]. No atomics, no LDS, 16 waves/CU.
// ---------------------------------------------------------------------------
__global__ __launch_bounds__(256, 4) void agg_kernel(
        const unsigned short* __restrict__ msgws, const int* __restrict__ offs,
        const int* __restrict__ cnt, const int* __restrict__ meta,
        const float* __restrict__ h, const float* __restrict__ weight,
        const float* __restrict__ norm, float* __restrict__ out) {
    int wv = threadIdx.x >> 6, lane = threadIdx.x & 63;
    int n = blockIdx.x * 4 + wv;
    if (n >= N_NODES) return;
    int start = offs[n], deg = cnt[n];
    if (deg == 0 || lane >= OUT_FEAT / 2) return;
    const unsigned* mp = reinterpret_cast<const unsigned*>(msgws);
    float ax = 0.f, ay = 0.f;
    int k = start, end = start + deg;
    for (; k + 2 <= end; k += 2) {
        int m0 = meta[k], m1 = meta[k + 1];
        int s0 = m0 & 0xFFFF, s1 = m1 & 0xFFFF;
        int r0 = (unsigned)m0 >> 16, r1 = (unsigned)m1 >> 16;
        unsigned u0 = mp[(size_t)k * (MSGW / 2) + lane];
        unsigned u1 = mp[(size_t)(k + 1) * (MSGW / 2) + lane];
        float2 h0 = *reinterpret_cast<const float2*>(h + (size_t)s0 * IN_FEAT + 2 * lane);
        float2 w0 = *reinterpret_cast<const float2*>(weight + (size_t)r0 * OUT_FEAT + 2 * lane);
        float2 h1 = *reinterpret_cast<const float2*>(h + (size_t)s1 * IN_FEAT + 2 * lane);
        float2 w1 = *reinterpret_cast<const float2*>(weight + (size_t)r1 * OUT_FEAT + 2 * lane);
        ax += h0.x * w0.x + bf2f(u0 & 0xffffu) + h1.x * w1.x + bf2f(u1 & 0xffffu);
        ay += h0.y * w0.y + bf2f(u0 >> 16) + h1.y * w1.y + bf2f(u1 >> 16);
    }
    if (k < end) {
        int m0 = meta[k];
        int s0 = m0 & 0xFFFF, r0 = (unsigned)m0 >> 16;
        unsigned u0 = mp[(size_t)k * (MSGW / 2) + lane];
        float2 h0 = *reinterpret_cast<const float2*>(h + (size_t)s0 * IN_FEAT + 2 * lane);
        float2 w0 = *reinterpret_cast<const float2*>(weight + (size_t)r0 * OUT_FEAT + 2 * lane);
        ax += h0.x * w0.x + bf2f(u0 & 0xffffu);
        ay += h0.y * w0.y + bf2f(u0 >> 16);
    }
    float nm = norm[n];
    float2* op = reinterpret_cast<float2*>(out + (size_t)n * OUT_FEAT) + lane;
    float2 curv = *op;
    curv.x += ax * nm; curv.y += ay * nm;
    *op = curv;
}

extern "C" void kernel_launch(void* const* d_in, const int* in_sizes, int n_in,
                              void* d_out, int out_size, void* d_ws, size_t ws_size,
                              hipStream_t stream) {
    const float* h      = (const float*)d_in[0];
    const float* efeat  = (const float*)d_in[1];
    const float* norm   = (const float*)d_in[2];
    const float* weight = (const float*)d_in[3];
    const float* attn   = (const float*)d_in[4];
    const float* fc_w   = (const float*)d_in[5];
    const float* loop_w = (const float*)d_in[6];
    const int*   rel    = (const int*)d_in[7];
    const int*   src    = (const int*)d_in[8];
    const int*   dst    = (const int*)d_in[9];
    float* out = (float*)d_out;

    char* ws = (char*)d_ws;
    unsigned short* Bimg  = (unsigned short*)(ws + WS_B);
    unsigned short* LWimg = (unsigned short*)(ws + WS_LW);
    int* cnt     = (int*)(ws + WS_CNT);
    int* offs    = (int*)(ws + WS_OFFS);
    int* cursor  = (int*)(ws + WS_CURSOR);
    int* bsum    = (int*)(ws + WS_BSUM);
    int* slotmap = (int*)(ws + WS_SLOT);
    int* meta    = (int*)(ws + WS_META);
    unsigned short* msgws = (unsigned short*)(ws + WS_MSG);

    build_B<<<(BROWS * 16 + 255) / 256, 256, 0, stream>>>(fc_w, Bimg);
    build_LW<<<(NPH * 16 + 255) / 256, 256, 0, stream>>>(loop_w, LWimg);
    loop_gemm<<<(N_NODES + MB - 1) / MB, 512, 0, stream>>>(h, LWimg, out);

    const int ntiles = N_EDGES / 16;

    if (ws_size >= (size_t)WS_NEEDED) {
        hipMemsetAsync(cnt, 0, NNODES_PAD * sizeof(int), stream);
        hist_kernel<<<(N_EDGES + 511) / 512, 512, 0, stream>>>(dst, cnt);
        scan1<<<NNODES_PAD / 1024, 1024, 0, stream>>>(cnt, offs, bsum);
        scan2<<<1, 64, 0, stream>>>(bsum);
        scan3<<<NNODES_PAD / 1024, 1024, 0, stream>>>(offs, bsum, cursor);
        scatter_kernel<<<(N_EDGES + 511) / 512, 512, 0, stream>>>(
            dst, src, rel, cursor, slotmap, meta);

        feat_kernel<true><<<512, 512, 0, stream>>>(
            efeat, rel, Bimg, attn, h, weight, norm, src, dst, slotmap,
            out, msgws, ntiles);
        agg_kernel<<<(N_NODES + 3) / 4, 256, 0, stream>>>(
            msgws, offs, cnt, meta, h, weight, norm, out);
    } else {
        feat_kernel<false><<<512, 512, 0, stream>>>(
            efeat, rel, Bimg, attn, h, weight, norm, src, dst, nullptr,
            out, msgws, ntiles);
    }
}